// Round 22
// baseline (669.113 us; speedup 1.0000x reference)
//
#include <hip/hip_runtime.h>
#include <hip/hip_cooperative_groups.h>
#include <math.h>

#define BATCH 64
#define HH 256
#define WW 256
#define HW 65536            // 256*256 pixels per image
#define NPIX (BATCH * HW)   // 4194304
#define NBINS 50
#define SENT_P 0x7FFFFFFF   // background marker

#define TW 64
#define TH 32
#define TN (TW * TH)        // 2048
#define TILES_X (WW / TW)   // 4
#define TILES_PER_IMG 32
#define EDGES_PER_IMG 2560  // 3*256 vertical + 7*256 horizontal
#define LIST_STRIDE 32768   // power of 2
#define MEGA_CHUNKS 32      // hist chunks/image in coop path
#define LEG_CHUNKS 8        // hist chunks/image in legacy path

namespace cg = cooperative_groups;

__device__ __forceinline__ int aload(const int* p) {
    return __hip_atomic_load(p, __ATOMIC_RELAXED, __HIP_MEMORY_SCOPE_AGENT);
}
__device__ __forceinline__ void astore(int* p, int v) {
    __hip_atomic_store(p, v, __ATOMIC_RELAXED, __HIP_MEMORY_SCOPE_AGENT);
}

__device__ __forceinline__ int runstart64(unsigned long long m, int c) {
    unsigned long long sh = (~m) << (63 - c);
    return sh ? (c - __clzll(sh) + 1) : 0;
}
__device__ __forceinline__ int runlen64(unsigned long long m, int c) {
    unsigned long long sh = ~(m >> c);
    return sh ? (__ffsll(sh) - 1) : 64;
}
// wave argmax: max val, tie -> min idx (== np first-occurrence)
__device__ __forceinline__ void wave_argmax(int& bv, int& bi) {
#pragma unroll
    for (int off = 32; off > 0; off >>= 1) {
        int ov = __shfl_xor(bv, off);
        int oi = __shfl_xor(bi, off);
        if (ov > bv || (ov == bv && oi < bi)) { bv = ov; bi = oi; }
    }
}

// ---- LDS union-find over run-start nodes ----
__device__ __forceinline__ int lfind(int* lp, int x) {
    int p = lp[x];
    while (p != x) { int gp = lp[p]; if (gp != p) lp[x] = gp; x = gp; p = lp[x]; }
    return x;
}
__device__ __forceinline__ void lunite(int* lp, int a, int b) {
    int ra = lfind(lp, a), rb = lfind(lp, b);
    while (ra != rb) {
        int lo = min(ra, rb), hi = max(ra, rb);
        int old = atomicMin(&lp[hi], lo);
        if (old == hi) return;
        ra = lfind(lp, lo); rb = lfind(lp, old);
    }
}
__device__ __forceinline__ int lfindm(int* lp, int x) {
    while (true) {
        int p = lp[x] & 0xFFFF;
        if (p == x) return x;
        int gp = lp[p] & 0xFFFF;
        if (gp != p) lp[x] = gp;
        x = gp;
    }
}

// ---- shared tile-CC body (R21-proven) ----
// CHUNKS: hist partials per image. AGENT: agent-scope (coherent-point) output
// stores for same-kernel cross-XCD visibility (coop path).
template<int CHUNKS, bool AGENT>
__device__ __forceinline__ void tile_cc_body(
    const float* __restrict__ att, const int* __restrict__ histp,
    int* parent, int* cnt, int* list, int* rootcnt,
    int b, int tile, int t, int* lp, unsigned int* msk32)
{
    const int ln = t & 63;
    const int wv = t >> 6;
    const int tr0 = (tile / TILES_X) * TH;
    const int tc0 = (tile % TILES_X) * TW;
    const float* A = att + (size_t)b * HW;

    // threshold (R11-proven f64 semantics), per-wave
    int h_ln = 0;
    if (ln < NBINS)
        for (int c = 0; c < CHUNKS; ++c) h_ln += histp[(b * CHUNKS + c) * 64 + ln];
    int bv = (ln < NBINS) ? h_ln : -1, bi = ln;
    wave_argmax(bv, bi);
    const int ind_max = bi;
    int bv2 = (ln < NBINS && ln > ind_max) ? h_ln : -1, bi2 = ln;
    wave_argmax(bv2, bi2);
    const double tv = (double)bi2 / 50.0;

    if (t < TH * 2) msk32[t] = 0;
    __syncthreads();

    // Phase 1: vectorized fg -> nibble atomicOr into row masks
    for (int i = t; i < TN / 4; i += 256) {
        int r = i >> 4, c4 = (i & 15) * 4;
        float4 v = *(const float4*)(A + (tr0 + r) * WW + tc0 + c4);
        unsigned nib = (((double)v.x > tv) ? 1u : 0u)
                     | (((double)v.y > tv) ? 2u : 0u)
                     | (((double)v.z > tv) ? 4u : 0u)
                     | (((double)v.w > tv) ? 8u : 0u);
        if (nib) atomicOr(&msk32[r * 2 + (c4 >> 5)], nib << (c4 & 31));
    }
    __syncthreads();

    // Phase 1b: init lp at run starts
    for (int k = 0; k < TH / 4; ++k) {
        int r = wv + 4 * k;
        unsigned long long m = (unsigned long long)msk32[r * 2]
                             | ((unsigned long long)msk32[r * 2 + 1] << 32);
        if (((m >> ln) & 1ull) && (ln == 0 || !((m >> (ln - 1)) & 1ull)))
            lp[r * TW + ln] = r * TW + ln;
    }
    __syncthreads();

    // Phase 2: vertical unions, one per overlap segment
    for (int k = 0; k < TH / 4; ++k) {
        int r = wv + 4 * k;
        if (r >= TH - 1) continue;
        unsigned long long m0 = (unsigned long long)msk32[r * 2]
                              | ((unsigned long long)msk32[r * 2 + 1] << 32);
        unsigned long long m1 = (unsigned long long)msk32[(r + 1) * 2]
                              | ((unsigned long long)msk32[(r + 1) * 2 + 1] << 32);
        unsigned long long ov = m0 & m1;
        if (((ov >> ln) & 1ull) && (ln == 0 || !((ov >> (ln - 1)) & 1ull)))
            lunite(lp, r * TW + runstart64(m0, ln),
                       (r + 1) * TW + runstart64(m1, ln));
    }
    __syncthreads();

    // Phase 3: deposit run lengths at local roots
    for (int k = 0; k < TH / 4; ++k) {
        int r = wv + 4 * k;
        unsigned long long m = (unsigned long long)msk32[r * 2]
                             | ((unsigned long long)msk32[r * 2 + 1] << 32);
        if (((m >> ln) & 1ull) && (ln == 0 || !((m >> (ln - 1)) & 1ull))) {
            int L = runlen64(m, ln);
            int root = lfindm(lp, r * TW + ln);
            atomicAdd(&lp[root], L << 16);
        }
    }
    __syncthreads();

    // Phase 4: write PURE parent; roots zero cnt + append (groot,size-1) to list
    int* P = parent + (size_t)b * HW;
    for (int i = t; i < TN / 4; i += 256) {
        int r = i >> 4, c4 = (i & 15) * 4;
        unsigned long long m = (unsigned long long)msk32[r * 2]
                             | ((unsigned long long)msk32[r * 2 + 1] << 32);
        int w[4];
#pragma unroll
        for (int j = 0; j < 4; ++j) {
            int c = c4 + j, l = r * TW + c;
            if (!((m >> c) & 1ull)) { w[j] = SENT_P; continue; }
            int node = r * TW + runstart64(m, c);
            int root = lfindm(lp, node);
            int groot = (tr0 + (root >> 6)) * WW + tc0 + (root & (TW - 1));
            w[j] = groot;
            if (l == root) {
                int size = lp[root] >> 16;             // 1..2048
                int idx = atomicAdd(&rootcnt[b], 1);
                if constexpr (AGENT) {
                    astore(&cnt[(size_t)b * HW + groot], 0);
                    astore(&list[b * LIST_STRIDE + idx], groot | ((size - 1) << 16));
                } else {
                    cnt[(size_t)b * HW + groot] = 0;
                    list[b * LIST_STRIDE + idx] = groot | ((size - 1) << 16);
                }
            }
        }
        int* dst = P + (tr0 + r) * WW + tc0 + c4;
        if constexpr (AGENT) {
            astore(dst + 0, w[0]); astore(dst + 1, w[1]);
            astore(dst + 2, w[2]); astore(dst + 3, w[3]);
        } else {
            *(int4*)dst = make_int4(w[0], w[1], w[2], w[3]);
        }
    }
}

// ---- global union-find (agent-scope, R14-proven) ----
__device__ __forceinline__ int findroot_h(int* P, int x) {
    int p = aload(P + x);
    while (p != x) {
        int gp = aload(P + p);
        astore(P + x, gp);
        x = gp; p = aload(P + x);
    }
    return x;
}
__device__ __forceinline__ void unite(int* P, int a, int b) {
    int ra = findroot_h(P, a);
    int rb = findroot_h(P, b);
    while (ra != rb) {
        int lo = min(ra, rb), hi = max(ra, rb);
        int old = atomicMin(&P[hi], lo);
        if (old == hi) return;
        ra = findroot_h(P, lo);
        rb = findroot_h(P, old);
    }
}
__device__ __forceinline__ void do_edge(int* parent, int g) {
    int b = g / EDGES_PER_IMG, e = g % EDGES_PER_IMG;
    int* P = parent + (size_t)b * HW;
    int l, m;
    if (e < 768) {          // vertical: cols {63,127,191}
        int k = e / 256, row = e & 255;
        l = row * WW + (TW - 1 + TW * k); m = l + 1;
    } else {                // horizontal: rows {31,63,...,223}
        int e2 = e - 768;
        int k = e2 / 256, col = e2 & 255;
        l = (TH - 1 + TH * k) * WW + col; m = l + WW;
    }
    if (aload(P + l) != SENT_P && aload(P + m) != SENT_P) unite(P, l, m);
}

// ================== cooperative mega-kernel (phases A-D) ==================
__global__ __launch_bounds__(256, 8)
void k_mega(const float* __restrict__ att, int* parent, int* cnt,
            int* list, int* rootcnt, int* histp) {
    cg::grid_group grid = cg::this_grid();
    __shared__ int lp[TN];
    __shared__ unsigned int msk32[TH * 2];
    __shared__ int h[64];
    const int t = threadIdx.x;
    const int gtid = blockIdx.x * 256 + t;
    const int G = gridDim.x * 256;

    // Phase A: hist partials (32 chunks/image) + zero rootcnt
    if (gtid < BATCH) astore(rootcnt + gtid, 0);
    for (int ci = blockIdx.x; ci < BATCH * MEGA_CHUNKS; ci += gridDim.x) {
        int b = ci >> 5, c = ci & 31;
        if (t < 64) h[t] = 0;
        __syncthreads();
        const float4* src = (const float4*)(att + (size_t)b * HW) + c * 512;
        for (int i = t; i < 512; i += 256) {
            float4 v = src[i];
            atomicAdd(&h[min((int)(v.x * 50.0f), 49)], 1);
            atomicAdd(&h[min((int)(v.y * 50.0f), 49)], 1);
            atomicAdd(&h[min((int)(v.z * 50.0f), 49)], 1);
            atomicAdd(&h[min((int)(v.w * 50.0f), 49)], 1);
        }
        __syncthreads();
        if (t < NBINS) astore(&histp[ci * 64 + t], h[t]);
        __syncthreads();                       // protect h reuse
    }
    __threadfence(); grid.sync();

    // Phase B: threshold + tile CC (agent-scope outputs)
    for (int ti = blockIdx.x; ti < BATCH * TILES_PER_IMG; ti += gridDim.x) {
        tile_cc_body<MEGA_CHUNKS, true>(att, histp, parent, cnt, list, rootcnt,
                                        ti >> 5, ti & 31, t, lp, msk32);
        __syncthreads();                       // protect lp/msk reuse
    }
    __threadfence(); grid.sync();

    // Phase C: boundary merge
    for (int e = gtid; e < BATCH * EDGES_PER_IMG; e += G) do_edge(parent, e);
    __threadfence(); grid.sync();

    // Phase D: accumulate (aload walks: topology frozen at coherent point)
    for (int x = gtid; x < BATCH * LIST_STRIDE; x += G) {
        int b = x >> 15, i = x & (LIST_STRIDE - 1);
        if (i >= aload(rootcnt + b)) continue;
        int e = aload(&list[b * LIST_STRIDE + i]);
        int xi = e & 0xFFFF;
        int size = (e >> 16) + 1;
        int* P = parent + (size_t)b * HW;
        int p = aload(P + xi);
        while (p != xi) { xi = p; p = aload(P + xi); }
        atomicAdd(&cnt[(size_t)b * HW + xi], size);
    }
}

// ================== legacy kernels (R21-proven fallback) ==================
__global__ void k_hist(const float* __restrict__ att, int* __restrict__ histp,
                       int* __restrict__ rootcnt) {
    __shared__ int h[NBINS];
    const int b = blockIdx.y, c = blockIdx.x, t = threadIdx.x;
    if (c == 0 && t == 0) rootcnt[b] = 0;
    if (t < NBINS) h[t] = 0;
    __syncthreads();
    const float4* src = (const float4*)(att + (size_t)b * HW) + c * 2048;
    for (int i = t; i < 2048; i += 256) {
        float4 v = src[i];
        atomicAdd(&h[min((int)(v.x * 50.0f), 49)], 1);
        atomicAdd(&h[min((int)(v.y * 50.0f), 49)], 1);
        atomicAdd(&h[min((int)(v.z * 50.0f), 49)], 1);
        atomicAdd(&h[min((int)(v.w * 50.0f), 49)], 1);
    }
    __syncthreads();
    if (t < NBINS) histp[(b * LEG_CHUNKS + c) * 64 + t] = h[t];
}

__global__ __launch_bounds__(256)
void k_init_cc(const float* __restrict__ att, const int* __restrict__ histp,
               int* parent, int* cnt, int* list, int* rootcnt) {
    __shared__ int lp[TN];
    __shared__ unsigned int msk32[TH * 2];
    tile_cc_body<LEG_CHUNKS, false>(att, histp, parent, cnt, list, rootcnt,
                                    blockIdx.y, blockIdx.x, threadIdx.x, lp, msk32);
}

__global__ void k_bmerge(int* parent) {
    int g = blockIdx.x * blockDim.x + threadIdx.x;
    if (g < BATCH * EDGES_PER_IMG) do_edge(parent, g);
}

__global__ void k_acc(const int* __restrict__ parent, int* __restrict__ cnt,
                      const int* __restrict__ list, const int* __restrict__ rootcnt) {
    int g = blockIdx.x * blockDim.x + threadIdx.x;
    int b = g / LIST_STRIDE, i = g - b * LIST_STRIDE;
    if (b >= BATCH || i >= rootcnt[b]) return;
    int e = list[b * LIST_STRIDE + i];
    int x = e & 0xFFFF;
    int size = (e >> 16) + 1;
    const int* P = parent + (size_t)b * HW;
    int p = P[x];
    while (p != x) { x = p; p = P[x]; }
    atomicAdd(&cnt[(size_t)b * HW + x], size);
}

// ---- final: plain L1-hot walk + cnt lookup (works after either path) ----
__global__ void k_final(const float* __restrict__ att, const int* __restrict__ parent,
                        const int* __restrict__ cnt, float* __restrict__ out) {
    int g = blockIdx.x * blockDim.x + threadIdx.x;
    int base = g * 4;
    if (base >= NPIX) return;
    const int* P = parent + (base & ~(HW - 1));
    const int* C = cnt + (base & ~(HW - 1));
    float4 v = ((const float4*)att)[g];
    int4 pv = ((const int4*)parent)[g];
    int vv[4] = {pv.x, pv.y, pv.z, pv.w};
    float xs[4] = {v.x, v.y, v.z, v.w};
    float ys[4];
#pragma unroll
    for (int j = 0; j < 4; ++j) {
        float x = xs[j];
        int w = vv[j];
        if (w == SENT_P) { ys[j] = x; continue; }
        int xi = w, p = P[xi];
        while (p != xi) { xi = p; p = P[xi]; }
        float a = (float)C[xi];
        ys[j] = powf(x, 1.0f / sqrtf(a));
    }
    ((float4*)out)[g] = make_float4(ys[0], ys[1], ys[2], ys[3]);
}

// ================= tiny-ws fallback: R11-proven monolith =================
__global__ __launch_bounds__(1024)
void k_all(const float* __restrict__ att, float* out) {
    const int b = blockIdx.x;
    const int t = threadIdx.x;
    const float* A = att + (size_t)b * HW;
    int* L = (int*)out + (size_t)b * HW;
    __shared__ int hist[NBINS];
    __shared__ double s_thr;
    __shared__ int s_changed;
    for (int i = t; i < NBINS; i += 1024) hist[i] = 0;
    if (t == 0) s_changed = 0;
    __syncthreads();
    const float4* src4 = (const float4*)A;
    for (int i = t; i < HW / 4; i += 1024) {
        float4 v = src4[i];
        atomicAdd(&hist[min((int)(v.x * 50.0f), 49)], 1);
        atomicAdd(&hist[min((int)(v.y * 50.0f), 49)], 1);
        atomicAdd(&hist[min((int)(v.z * 50.0f), 49)], 1);
        atomicAdd(&hist[min((int)(v.w * 50.0f), 49)], 1);
    }
    __syncthreads();
    if (t == 0) {
        int ind_max = 0, bv = hist[0];
        for (int j = 1; j < NBINS; ++j)
            if (hist[j] > bv) { bv = hist[j]; ind_max = j; }
        int ind_sec = 0, bv2 = -1;
        for (int j = 1; j < NBINS; ++j) {
            int v = (j > ind_max) ? hist[j] : -1;
            if (v > bv2) { bv2 = v; ind_sec = j; }
        }
        s_thr = (double)ind_sec / 50.0;
    }
    __syncthreads();
    const double tv = s_thr;
    for (int i = t; i < HW / 4; i += 1024) {
        float4 v = src4[i];
        int l = i * 4;
        astore(L + l + 0, ((double)v.x > tv) ? (l + 0) : SENT_P);
        astore(L + l + 1, ((double)v.y > tv) ? (l + 1) : SENT_P);
        astore(L + l + 2, ((double)v.z > tv) ? (l + 2) : SENT_P);
        astore(L + l + 3, ((double)v.w > tv) ? (l + 3) : SENT_P);
    }
    __syncthreads();
    for (;;) {
        int changed = 0;
        for (int p = t; p < HW; p += 1024) {
            int v = aload(L + p);
            if (v == SENT_P) continue;
            int m = v;
            int col = p & (WW - 1), row = p >> 8;
            if (col > 0)      m = min(m, aload(L + p - 1));
            if (col < WW - 1) m = min(m, aload(L + p + 1));
            if (row > 0)      m = min(m, aload(L + p - WW));
            if (row < HH - 1) m = min(m, aload(L + p + WW));
            m = min(m, aload(L + m));
            if (m < v) { astore(L + p, m); changed = 1; }
        }
        if (changed) s_changed = 1;
        __syncthreads();
        int ch = s_changed;
        __syncthreads();
        if (!ch) break;
        if (t == 0) s_changed = 0;
        __syncthreads();
    }
    for (int p = t; p < HW; p += 1024) {
        int v = aload(L + p);
        if (v == SENT_P) continue;
        int lo = v & 0xFFFF;
        if (lo != p) atomicAdd((unsigned int*)(L + lo), 0x10000u);
    }
    __syncthreads();
    for (int p = t; p < HW; p += 1024) {
        int v = aload(L + p);
        if (v == SENT_P) continue;
        int lo = v & 0xFFFF;
        if (lo != p) astore(L + p, aload(L + lo));
    }
    __syncthreads();
    for (int p = t; p < HW; p += 1024) {
        float x = A[p];
        unsigned v = (unsigned)aload(L + p);
        float y = x;
        if (v != (unsigned)SENT_P) {
            float a = (float)((v >> 16) + 1u);
            y = powf(x, 1.0f / sqrtf(a));
        }
        out[(size_t)b * HW + p] = y;
    }
}

extern "C" void kernel_launch(void* const* d_in, const int* in_sizes, int n_in,
                              void* d_out, int out_size, void* d_ws, size_t ws_size,
                              hipStream_t stream) {
    const float* att = (const float*)d_in[0];
    float* out = (float*)d_out;
    (void)in_sizes; (void)n_in; (void)out_size;

    const size_t PAR_B  = (size_t)NPIX * 4;                        // 16 MB
    const size_t CNT_B  = (size_t)NPIX * 4;                        // 16 MB
    const size_t LIST_B = (size_t)BATCH * LIST_STRIDE * 4;         // 8 MB
    const size_t HIST_B = (size_t)BATCH * MEGA_CHUNKS * 64 * 4;    // 512 KB
    if (ws_size < PAR_B + CNT_B + LIST_B + HIST_B + 1024) {
        k_all<<<BATCH, 1024, 0, stream>>>(att, out);               // proven fallback
        return;
    }
    int* parent  = (int*)d_ws;
    int* cnt     = (int*)((char*)d_ws + PAR_B);
    int* list    = (int*)((char*)d_ws + PAR_B + CNT_B);
    int* histp   = (int*)((char*)d_ws + PAR_B + CNT_B + LIST_B);
    int* rootcnt = (int*)((char*)d_ws + PAR_B + CNT_B + LIST_B + HIST_B);

    // try cooperative mega-kernel (2-dispatch path)
    bool coop = false;
    int maxBlocksPerCU = 0;
    hipError_t oe = hipOccupancyMaxActiveBlocksPerMultiprocessor(
        &maxBlocksPerCU, reinterpret_cast<const void*>(&k_mega), 256, 0);
    int numCU = 0;
    if (hipDeviceGetAttribute(&numCU, hipDeviceAttributeMultiprocessorCount, 0)
        != hipSuccess || numCU <= 0) numCU = 256;
    if (oe == hipSuccess && maxBlocksPerCU > 0) {
        int grid = maxBlocksPerCU * numCU;
        if (grid > BATCH * TILES_PER_IMG) grid = BATCH * TILES_PER_IMG;   // 2048
        void* args[] = { (void*)&att, (void*)&parent, (void*)&cnt,
                         (void*)&list, (void*)&rootcnt, (void*)&histp };
        hipError_t le = hipLaunchCooperativeKernel(
            reinterpret_cast<const void*>(&k_mega), dim3(grid), dim3(256),
            args, 0, stream);
        coop = (le == hipSuccess);
    }
    if (!coop) {   // legacy 4-dispatch chain (R21-proven)
        k_hist<<<dim3(LEG_CHUNKS, BATCH), 256, 0, stream>>>(att, histp, rootcnt);
        k_init_cc<<<dim3(TILES_PER_IMG, BATCH), 256, 0, stream>>>(att, histp, parent,
                                                                  cnt, list, rootcnt);
        k_bmerge<<<(BATCH * EDGES_PER_IMG + 255) / 256, 256, 0, stream>>>(parent);
        k_acc<<<(BATCH * LIST_STRIDE) / 256, 256, 0, stream>>>(parent, cnt, list,
                                                               rootcnt);
    }
    k_final<<<NPIX / (256 * 4), 256, 0, stream>>>(att, parent, cnt, out);
}

// Round 23
// 341.774 us; speedup vs baseline: 1.9578x; 1.9578x over previous
//
#include <hip/hip_runtime.h>
#include <math.h>

#define BATCH 64
#define HH 256
#define WW 256
#define HW 65536            // 256*256 pixels per image
#define NPIX (BATCH * HW)   // 4194304
#define NBINS 50
#define SENT_P 0x7FFFFFFF   // background marker

#define TW 64
#define TH 32
#define TN (TW * TH)        // 2048
#define TILES_X (WW / TW)   // 4
#define TILES_PER_IMG 32
#define EDGES_PER_IMG 2560  // 3*256 vertical + 7*256 horizontal
#define LIST_STRIDE 32768
#define CHUNKS 8            // hist chunks/image

__device__ __forceinline__ int aload(const int* p) {
    return __hip_atomic_load(p, __ATOMIC_RELAXED, __HIP_MEMORY_SCOPE_AGENT);
}
__device__ __forceinline__ void astore(int* p, int v) {
    __hip_atomic_store(p, v, __ATOMIC_RELAXED, __HIP_MEMORY_SCOPE_AGENT);
}

__device__ __forceinline__ int runstart64(unsigned long long m, int c) {
    unsigned long long sh = (~m) << (63 - c);
    return sh ? (c - __clzll(sh) + 1) : 0;
}
__device__ __forceinline__ int runlen64(unsigned long long m, int c) {
    unsigned long long sh = ~(m >> c);
    return sh ? (__ffsll(sh) - 1) : 64;
}
// wave argmax: max val, tie -> min idx (== np first-occurrence)
__device__ __forceinline__ void wave_argmax(int& bv, int& bi) {
#pragma unroll
    for (int off = 32; off > 0; off >>= 1) {
        int ov = __shfl_xor(bv, off);
        int oi = __shfl_xor(bi, off);
        if (ov > bv || (ov == bv && oi < bi)) { bv = ov; bi = oi; }
    }
}

// ---- K1: histogram partials (8 blocks/image) + zero per-image counters ----
__global__ void k_hist(const float* __restrict__ att, int* __restrict__ histp,
                       int* __restrict__ rootcnt, int* __restrict__ donecnt) {
    __shared__ int h[NBINS];
    const int b = blockIdx.y, c = blockIdx.x, t = threadIdx.x;
    if (c == 0 && t == 0) { rootcnt[b] = 0; donecnt[b] = 0; }   // kernel boundary publishes
    if (t < NBINS) h[t] = 0;
    __syncthreads();
    const float4* src = (const float4*)(att + (size_t)b * HW) + c * 2048;
    for (int i = t; i < 2048; i += 256) {
        float4 v = src[i];
        atomicAdd(&h[min((int)(v.x * 50.0f), 49)], 1);
        atomicAdd(&h[min((int)(v.y * 50.0f), 49)], 1);
        atomicAdd(&h[min((int)(v.z * 50.0f), 49)], 1);
        atomicAdd(&h[min((int)(v.w * 50.0f), 49)], 1);
    }
    __syncthreads();
    if (t < NBINS) histp[(b * CHUNKS + c) * 64 + t] = h[t];
}

// ---- LDS union-find over run-start nodes ----
__device__ __forceinline__ int lfind(int* lp, int x) {
    int p = lp[x];
    while (p != x) { int gp = lp[p]; if (gp != p) lp[x] = gp; x = gp; p = lp[x]; }
    return x;
}
__device__ __forceinline__ void lunite(int* lp, int a, int b) {
    int ra = lfind(lp, a), rb = lfind(lp, b);
    while (ra != rb) {
        int lo = min(ra, rb), hi = max(ra, rb);
        int old = atomicMin(&lp[hi], lo);
        if (old == hi) return;
        ra = lfind(lp, lo); rb = lfind(lp, old);
    }
}
__device__ __forceinline__ int lfindm(int* lp, int x) {
    while (true) {
        int p = lp[x] & 0xFFFF;
        if (p == x) return x;
        int gp = lp[p] & 0xFFFF;
        if (gp != p) lp[x] = gp;
        x = gp;
    }
}

// ---- global union-find (agent-scope, R14-proven) ----
__device__ __forceinline__ int findroot_h(int* P, int x) {
    int p = aload(P + x);
    while (p != x) {
        int gp = aload(P + p);
        astore(P + x, gp);
        x = gp; p = aload(P + x);
    }
    return x;
}
__device__ __forceinline__ void unite(int* P, int a, int b) {
    int ra = findroot_h(P, a);
    int rb = findroot_h(P, b);
    while (ra != rb) {
        int lo = min(ra, rb), hi = max(ra, rb);
        int old = atomicMin(&P[hi], lo);
        if (old == hi) return;
        ra = findroot_h(P, lo);
        rb = findroot_h(P, old);
    }
}
__device__ __forceinline__ void do_edge_img(int* P, int e) {
    int l, m;
    if (e < 768) {          // vertical: cols {63,127,191}
        int k = e / 256, row = e & 255;
        l = row * WW + (TW - 1 + TW * k); m = l + 1;
    } else {                // horizontal: rows {31,63,...,223}
        int e2 = e - 768;
        int k = e2 / 256, col = e2 & 255;
        l = (TH - 1 + TH * k) * WW + col; m = l + WW;
    }
    if (aload(P + l) != SENT_P && aload(P + m) != SENT_P) unite(P, l, m);
}

// ---- K2: fused threshold + tile CC + (last block per image) bmerge + acc ----
__global__ __launch_bounds__(256)
void k_init_cc(const float* __restrict__ att, const int* __restrict__ histp,
               int* parent, int* cnt, int* list,
               int* rootcnt, int* donecnt) {
    __shared__ int lp[TN];
    __shared__ unsigned int msk32[TH * 2];
    __shared__ int s_last;
    const int tile = blockIdx.x;
    const int b = blockIdx.y;
    const int t = threadIdx.x;
    const int ln = t & 63, wv = t >> 6;
    const int tr0 = (tile / TILES_X) * TH;
    const int tc0 = (tile % TILES_X) * TW;
    const float* A = att + (size_t)b * HW;

    // Phase 0: per-wave inline threshold (R11-proven f64 semantics)
    int h_ln = 0;
    if (ln < NBINS)
        for (int c = 0; c < CHUNKS; ++c) h_ln += histp[(b * CHUNKS + c) * 64 + ln];
    int bv = (ln < NBINS) ? h_ln : -1, bi = ln;
    wave_argmax(bv, bi);
    const int ind_max = bi;
    int bv2 = (ln < NBINS && ln > ind_max) ? h_ln : -1, bi2 = ln;
    wave_argmax(bv2, bi2);
    const double tv = (double)bi2 / 50.0;

    if (t < TH * 2) msk32[t] = 0;
    __syncthreads();

    // Phase 1: vectorized fg -> nibble atomicOr into row masks
    for (int i = t; i < TN / 4; i += 256) {
        int r = i >> 4, c4 = (i & 15) * 4;
        float4 v = *(const float4*)(A + (tr0 + r) * WW + tc0 + c4);
        unsigned nib = (((double)v.x > tv) ? 1u : 0u)
                     | (((double)v.y > tv) ? 2u : 0u)
                     | (((double)v.z > tv) ? 4u : 0u)
                     | (((double)v.w > tv) ? 8u : 0u);
        if (nib) atomicOr(&msk32[r * 2 + (c4 >> 5)], nib << (c4 & 31));
    }
    __syncthreads();

    // Phase 1b: init lp at run starts
    for (int k = 0; k < TH / 4; ++k) {
        int r = wv + 4 * k;
        unsigned long long m = (unsigned long long)msk32[r * 2]
                             | ((unsigned long long)msk32[r * 2 + 1] << 32);
        if (((m >> ln) & 1ull) && (ln == 0 || !((m >> (ln - 1)) & 1ull)))
            lp[r * TW + ln] = r * TW + ln;
    }
    __syncthreads();

    // Phase 2: vertical unions, one per overlap segment
    for (int k = 0; k < TH / 4; ++k) {
        int r = wv + 4 * k;
        if (r >= TH - 1) continue;
        unsigned long long m0 = (unsigned long long)msk32[r * 2]
                              | ((unsigned long long)msk32[r * 2 + 1] << 32);
        unsigned long long m1 = (unsigned long long)msk32[(r + 1) * 2]
                              | ((unsigned long long)msk32[(r + 1) * 2 + 1] << 32);
        unsigned long long ov = m0 & m1;
        if (((ov >> ln) & 1ull) && (ln == 0 || !((ov >> (ln - 1)) & 1ull)))
            lunite(lp, r * TW + runstart64(m0, ln),
                       (r + 1) * TW + runstart64(m1, ln));
    }
    __syncthreads();

    // Phase 3: deposit run lengths at local roots
    for (int k = 0; k < TH / 4; ++k) {
        int r = wv + 4 * k;
        unsigned long long m = (unsigned long long)msk32[r * 2]
                             | ((unsigned long long)msk32[r * 2 + 1] << 32);
        if (((m >> ln) & 1ull) && (ln == 0 || !((m >> (ln - 1)) & 1ull))) {
            int L = runlen64(m, ln);
            int root = lfindm(lp, r * TW + ln);
            atomicAdd(&lp[root], L << 16);
        }
    }
    __syncthreads();

    // Phase 4: write PURE parent; roots zero cnt + append (groot,size-1) to list
    int* P = parent + (size_t)b * HW;
    for (int i = t; i < TN / 4; i += 256) {
        int r = i >> 4, c4 = (i & 15) * 4;
        unsigned long long m = (unsigned long long)msk32[r * 2]
                             | ((unsigned long long)msk32[r * 2 + 1] << 32);
        int w[4];
#pragma unroll
        for (int j = 0; j < 4; ++j) {
            int c = c4 + j, l = r * TW + c;
            if (!((m >> c) & 1ull)) { w[j] = SENT_P; continue; }
            int node = r * TW + runstart64(m, c);
            int root = lfindm(lp, node);
            int groot = (tr0 + (root >> 6)) * WW + tc0 + (root & (TW - 1));
            w[j] = groot;
            if (l == root) {
                int size = lp[root] >> 16;             // 1..2048
                cnt[(size_t)b * HW + groot] = 0;
                int idx = atomicAdd(&rootcnt[b], 1);
                list[b * LIST_STRIDE + idx] = groot | ((size - 1) << 16);
            }
        }
        *(int4*)(P + (tr0 + r) * WW + tc0 + c4) = make_int4(w[0], w[1], w[2], w[3]);
    }

    // ---- Phase 5: last-block-done -> per-image boundary merge + accumulate ----
    __threadfence();                 // push this block's plain writes to coherent point
    __syncthreads();                 // all threads fenced before the bump
    if (t == 0)
        s_last = (atomicAdd(&donecnt[b], 1) == TILES_PER_IMG - 1) ? 1 : 0;
    __syncthreads();
    if (!s_last) return;

    // This block is last for image b: every other block's writes are fenced to the
    // coherent point, and all our accesses below (aload/astore/atomicMin/atomicAdd)
    // bypass L1/L2, so no stale data is observable. Per-image partition: no other
    // block touches image b from here on.
    for (int e = t; e < EDGES_PER_IMG; e += 256) do_edge_img(P, e);
    __syncthreads();                 // unions drained (waitcnt before barrier)

    int n = aload(&rootcnt[b]);
    for (int i = t; i < n; i += 256) {
        int e = aload(&list[b * LIST_STRIDE + i]);
        int xi = e & 0xFFFF;
        int size = (e >> 16) + 1;
        int p = aload(P + xi);
        while (p != xi) { xi = p; p = aload(P + xi); }
        atomicAdd(&cnt[(size_t)b * HW + xi], size);    // memory-side RMW
    }
}

// ---- K3: finalize — plain L1-hot walk + cnt lookup (kernel boundary freezes) ----
__global__ void k_final(const float* __restrict__ att, const int* __restrict__ parent,
                        const int* __restrict__ cnt, float* __restrict__ out) {
    int g = blockIdx.x * blockDim.x + threadIdx.x;
    int base = g * 4;
    if (base >= NPIX) return;
    const int* P = parent + (base & ~(HW - 1));
    const int* C = cnt + (base & ~(HW - 1));
    float4 v = ((const float4*)att)[g];
    int4 pv = ((const int4*)parent)[g];
    int vv[4] = {pv.x, pv.y, pv.z, pv.w};
    float xs[4] = {v.x, v.y, v.z, v.w};
    float ys[4];
#pragma unroll
    for (int j = 0; j < 4; ++j) {
        float x = xs[j];
        int w = vv[j];
        if (w == SENT_P) { ys[j] = x; continue; }
        int xi = w, p = P[xi];
        while (p != xi) { xi = p; p = P[xi]; }     // depth ~1-2
        float a = (float)C[xi];
        ys[j] = powf(x, 1.0f / sqrtf(a));
    }
    ((float4*)out)[g] = make_float4(ys[0], ys[1], ys[2], ys[3]);
}

// ================= tiny-ws fallback: R11-proven monolith =================
__global__ __launch_bounds__(1024)
void k_all(const float* __restrict__ att, float* out) {
    const int b = blockIdx.x;
    const int t = threadIdx.x;
    const float* A = att + (size_t)b * HW;
    int* L = (int*)out + (size_t)b * HW;
    __shared__ int hist[NBINS];
    __shared__ double s_thr;
    __shared__ int s_changed;
    for (int i = t; i < NBINS; i += 1024) hist[i] = 0;
    if (t == 0) s_changed = 0;
    __syncthreads();
    const float4* src4 = (const float4*)A;
    for (int i = t; i < HW / 4; i += 1024) {
        float4 v = src4[i];
        atomicAdd(&hist[min((int)(v.x * 50.0f), 49)], 1);
        atomicAdd(&hist[min((int)(v.y * 50.0f), 49)], 1);
        atomicAdd(&hist[min((int)(v.z * 50.0f), 49)], 1);
        atomicAdd(&hist[min((int)(v.w * 50.0f), 49)], 1);
    }
    __syncthreads();
    if (t == 0) {
        int ind_max = 0, bv = hist[0];
        for (int j = 1; j < NBINS; ++j)
            if (hist[j] > bv) { bv = hist[j]; ind_max = j; }
        int ind_sec = 0, bv2 = -1;
        for (int j = 1; j < NBINS; ++j) {
            int v = (j > ind_max) ? hist[j] : -1;
            if (v > bv2) { bv2 = v; ind_sec = j; }
        }
        s_thr = (double)ind_sec / 50.0;
    }
    __syncthreads();
    const double tv = s_thr;
    for (int i = t; i < HW / 4; i += 1024) {
        float4 v = src4[i];
        int l = i * 4;
        astore(L + l + 0, ((double)v.x > tv) ? (l + 0) : SENT_P);
        astore(L + l + 1, ((double)v.y > tv) ? (l + 1) : SENT_P);
        astore(L + l + 2, ((double)v.z > tv) ? (l + 2) : SENT_P);
        astore(L + l + 3, ((double)v.w > tv) ? (l + 3) : SENT_P);
    }
    __syncthreads();
    for (;;) {
        int changed = 0;
        for (int p = t; p < HW; p += 1024) {
            int v = aload(L + p);
            if (v == SENT_P) continue;
            int m = v;
            int col = p & (WW - 1), row = p >> 8;
            if (col > 0)      m = min(m, aload(L + p - 1));
            if (col < WW - 1) m = min(m, aload(L + p + 1));
            if (row > 0)      m = min(m, aload(L + p - WW));
            if (row < HH - 1) m = min(m, aload(L + p + WW));
            m = min(m, aload(L + m));
            if (m < v) { astore(L + p, m); changed = 1; }
        }
        if (changed) s_changed = 1;
        __syncthreads();
        int ch = s_changed;
        __syncthreads();
        if (!ch) break;
        if (t == 0) s_changed = 0;
        __syncthreads();
    }
    for (int p = t; p < HW; p += 1024) {
        int v = aload(L + p);
        if (v == SENT_P) continue;
        int lo = v & 0xFFFF;
        if (lo != p) atomicAdd((unsigned int*)(L + lo), 0x10000u);
    }
    __syncthreads();
    for (int p = t; p < HW; p += 1024) {
        int v = aload(L + p);
        if (v == SENT_P) continue;
        int lo = v & 0xFFFF;
        if (lo != p) astore(L + p, aload(L + lo));
    }
    __syncthreads();
    for (int p = t; p < HW; p += 1024) {
        float x = A[p];
        unsigned v = (unsigned)aload(L + p);
        float y = x;
        if (v != (unsigned)SENT_P) {
            float a = (float)((v >> 16) + 1u);
            y = powf(x, 1.0f / sqrtf(a));
        }
        out[(size_t)b * HW + p] = y;
    }
}

extern "C" void kernel_launch(void* const* d_in, const int* in_sizes, int n_in,
                              void* d_out, int out_size, void* d_ws, size_t ws_size,
                              hipStream_t stream) {
    const float* att = (const float*)d_in[0];
    float* out = (float*)d_out;
    (void)in_sizes; (void)n_in; (void)out_size;

    const size_t PAR_B  = (size_t)NPIX * 4;                    // 16 MB
    const size_t CNT_B  = (size_t)NPIX * 4;                    // 16 MB
    const size_t LIST_B = (size_t)BATCH * LIST_STRIDE * 4;     // 8 MB
    const size_t HIST_B = (size_t)BATCH * CHUNKS * 64 * 4;     // 128 KB
    if (ws_size < PAR_B + CNT_B + LIST_B + HIST_B + 2048) {
        k_all<<<BATCH, 1024, 0, stream>>>(att, out);           // proven fallback
        return;
    }
    int* parent  = (int*)d_ws;
    int* cnt     = (int*)((char*)d_ws + PAR_B);
    int* list    = (int*)((char*)d_ws + PAR_B + CNT_B);
    int* histp   = (int*)((char*)d_ws + PAR_B + CNT_B + LIST_B);
    int* rootcnt = (int*)((char*)d_ws + PAR_B + CNT_B + LIST_B + HIST_B);
    int* donecnt = rootcnt + BATCH;

    k_hist<<<dim3(CHUNKS, BATCH), 256, 0, stream>>>(att, histp, rootcnt, donecnt);
    k_init_cc<<<dim3(TILES_PER_IMG, BATCH), 256, 0, stream>>>(att, histp, parent,
                                                              cnt, list, rootcnt,
                                                              donecnt);
    k_final<<<NPIX / (256 * 4), 256, 0, stream>>>(att, parent, cnt, out);
}

// Round 24
// 186.878 us; speedup vs baseline: 3.5805x; 1.8289x over previous
//
#include <hip/hip_runtime.h>
#include <math.h>

#define BATCH 64
#define HH 256
#define WW 256
#define HW 65536            // 256*256 pixels per image
#define NBINS 50
#define RUNCAP 32768        // max runs/image: 256 rows * 128 runs

// One block per image. Whole pipeline in LDS: histogram -> f64 threshold ->
// row bitmasks -> run-based union-find over run IDs -> size deposit at roots
// -> direct pow output. Zero global intermediates, zero cross-block traffic.

__device__ __forceinline__ void wave_argmax(int& bv, int& bi) {
#pragma unroll
    for (int off = 32; off > 0; off >>= 1) {
        int ov = __shfl_xor(bv, off);
        int oi = __shfl_xor(bi, off);
        if (ov > bv || (ov == bv && oi < bi)) { bv = ov; bi = oi; }
    }
}

// LDS union-find over run IDs (pure values during union phase)
__device__ __forceinline__ int lfind(int* lp, int x) {
    int p = lp[x];
    while (p != x) { int gp = lp[p]; if (gp != p) lp[x] = gp; x = gp; p = lp[x]; }
    return x;
}
__device__ __forceinline__ void lunite(int* lp, int a, int b) {
    int ra = lfind(lp, a), rb = lfind(lp, b);
    while (ra != rb) {
        int lo = min(ra, rb), hi = max(ra, rb);
        int old = atomicMin(&lp[hi], lo);
        if (old == hi) return;
        ra = lfind(lp, lo); rb = lfind(lp, old);
    }
}
// masked find (post-union: root slots carry size-1 in high 16 bits).
// Halving writes touch only NON-root slots with pure values (proven pattern).
__device__ __forceinline__ int lfindm(int* lp, int x) {
    while (true) {
        int p = lp[x] & 0xFFFF;
        if (p == x) return x;
        int gp = lp[p] & 0xFFFF;
        if (gp != p) lp[x] = gp;
        x = gp;
    }
}

// run id of the run containing col c of row r (bit c must be set in msk)
__device__ __forceinline__ int run_of(const unsigned (*rs)[8], const int* row_off,
                                      int r, int c) {
    int w = c >> 5, j = c & 31;
    int s = 0;
    for (int i = 0; i < w; ++i) s += __popc(rs[r][i]);
    s += __popc(rs[r][w] & (0xFFFFFFFFu >> (31 - j)));   // bits 0..j inclusive
    return row_off[r] + s - 1;
}

// consecutive-ones length in row mask starting at col c (crosses 32-bit words)
__device__ __forceinline__ int runlen_row(const unsigned* mrow, int c) {
    int len = 0;
    int wi = c >> 5, off = c & 31;
    while (wi < 8) {
        unsigned cur = mrow[wi] >> off;
        unsigned inv = ~cur;
        if (inv == 0u) { len += 32; }          // off==0 and full word of ones
        else {
            int n = __ffs(inv) - 1;            // trailing ones
            len += n;
            if (n < 32 - off) return len;      // run ends inside this word
        }
        ++wi; off = 0;
    }
    return len;
}

__global__ __launch_bounds__(1024)
void k_fused(const float* __restrict__ att, float* __restrict__ out) {
    __shared__ int      hist[64];
    __shared__ unsigned msk[HH][8];     // 8 KB  row bitmasks (32-bit words)
    __shared__ unsigned rs[HH][8];      // 8 KB  run-start bitmasks
    __shared__ int      row_off[HH + 1];
    __shared__ int      wsum[4];
    __shared__ int      parent[RUNCAP]; // 128 KB run-ID union-find

    const int b = blockIdx.x;
    const int t = threadIdx.x;
    const int ln = t & 63, wv = t >> 6;          // 16 waves
    const float* A = att + (size_t)b * HW;
    const float4* src4 = (const float4*)A;

    // ---- init ----
    for (int i = t; i < 64; i += 1024) hist[i] = 0;
    for (int i = t; i < HH * 8; i += 1024) ((unsigned*)msk)[i] = 0;
    __syncthreads();

    // ---- pass A: histogram (f32 trunc binning = port semantics) ----
    for (int i = t; i < HW / 4; i += 1024) {
        float4 v = src4[i];
        atomicAdd(&hist[min((int)(v.x * 50.0f), 49)], 1);
        atomicAdd(&hist[min((int)(v.y * 50.0f), 49)], 1);
        atomicAdd(&hist[min((int)(v.z * 50.0f), 49)], 1);
        atomicAdd(&hist[min((int)(v.w * 50.0f), 49)], 1);
    }
    __syncthreads();

    // ---- threshold: per-wave argmax chain (R11-proven f64 semantics) ----
    int h_ln = (ln < NBINS) ? hist[ln] : -1;
    int bv = h_ln, bi = ln;
    wave_argmax(bv, bi);
    const int ind_max = bi;                      // first-occurrence argmax
    int bv2 = (ln < NBINS && ln > ind_max) ? hist[ln] : -1, bi2 = ln;
    wave_argmax(bv2, bi2);                       // all-(-1) -> 0 (np edge case)
    const double tv = (double)bi2 / 50.0;        // FLOAT64 threshold

    // ---- pass B: fg masks (f64 compare) ----
    for (int i = t; i < HW / 4; i += 1024) {
        float4 v = src4[i];
        int r = i >> 6, c4 = (i & 63) * 4;
        unsigned nib = (((double)v.x > tv) ? 1u : 0u)
                     | (((double)v.y > tv) ? 2u : 0u)
                     | (((double)v.z > tv) ? 4u : 0u)
                     | (((double)v.w > tv) ? 8u : 0u);
        if (nib) atomicOr(&msk[r][c4 >> 5], nib << (c4 & 31));
    }
    __syncthreads();

    // ---- run-start masks: rs = m & ~((m<<1) | carry) ----
    for (int i = t; i < HH * 8; i += 1024) {
        int r = i >> 3, w = i & 7;
        unsigned m = msk[r][w];
        unsigned prev = (w == 0) ? 0u : msk[r][w - 1];
        rs[r][w] = m & ~((m << 1) | (prev >> 31));
    }
    __syncthreads();

    // ---- per-row run counts ----
    if (t < HH) {
        int s = 0;
#pragma unroll
        for (int w = 0; w < 8; ++w) s += __popc(rs[t][w]);
        row_off[t] = s;                          // counts (temp)
    }
    __syncthreads();

    // ---- exclusive scan of 256 counts (4 waves + cross-wave offsets) ----
    int v = (t < HH) ? row_off[t] : 0;
    int x = v;
#pragma unroll
    for (int off = 1; off < 64; off <<= 1) {
        int y = __shfl_up(x, off);
        if (ln >= off) x += y;
    }
    if (ln == 63 && wv < 4) wsum[wv] = x;
    __syncthreads();
    if (t < HH) {
        int base = 0;
        for (int w = 0; w < wv; ++w) base += wsum[w];
        row_off[t] = base + x - v;               // exclusive
        if (t == HH - 1) row_off[HH] = base + x; // total runs T
    }
    __syncthreads();

    // ---- init parent over T runs ----
    const int T = row_off[HH];
    for (int i = t; i < T; i += 1024) parent[i] = i;
    __syncthreads();

    // ---- vertical unions: one per overlap segment ----
    for (int rp = wv; rp < HH - 1; rp += 16) {
#pragma unroll
        for (int k = 0; k < 4; ++k) {
            unsigned long long m0 = ((unsigned long long)msk[rp][2 * k + 1] << 32)
                                  | msk[rp][2 * k];
            unsigned long long m1 = ((unsigned long long)msk[rp + 1][2 * k + 1] << 32)
                                  | msk[rp + 1][2 * k];
            unsigned long long ov = m0 & m1;
            if (!((ov >> ln) & 1ull)) continue;
            bool prevbit;
            if (ln > 0)      prevbit = (ov >> (ln - 1)) & 1ull;
            else if (k == 0) prevbit = false;
            else prevbit = ((msk[rp][2 * k - 1] & msk[rp + 1][2 * k - 1]) >> 31) & 1u;
            if (!prevbit) {
                int c = 64 * k + ln;
                lunite(parent, run_of(rs, row_off, rp, c),
                               run_of(rs, row_off, rp + 1, c));
            }
        }
    }
    __syncthreads();

    // ---- deposit run lengths at roots (root's own run deposits L-1 so the
    //      size field = size-1 <= 65535: no overflow even for all-fg image) ----
    for (int i = t; i < HH * 8; i += 1024) {
        int r = i >> 3, w = i & 7;
        unsigned bits = rs[r][w];
        if (!bits) continue;
        int base = row_off[r];
        for (int ww = 0; ww < w; ++ww) base += __popc(rs[r][ww]);
        int k = 0;
        while (bits) {
            int j = __ffs(bits) - 1;
            bits &= bits - 1;
            int c = w * 32 + j;
            int rid = base + k; ++k;
            int L = runlen_row(msk[r], c);
            int root = lfindm(parent, rid);
            unsigned dep = (unsigned)(rid == root ? L - 1 : L) << 16;
            if (dep) atomicAdd((unsigned*)&parent[root], dep);
        }
    }
    __syncthreads();

    // ---- pass C: output (pow for fg via run walk, identity for bg) ----
    float4* dst4 = (float4*)(out + (size_t)b * HW);
    for (int i = t; i < HW / 4; i += 1024) {
        float4 vv = src4[i];
        int r = i >> 6, c4 = (i & 63) * 4;
        unsigned mw = msk[r][c4 >> 5];
        float xs[4] = {vv.x, vv.y, vv.z, vv.w};
        float ys[4];
#pragma unroll
        for (int j = 0; j < 4; ++j) {
            float xx = xs[j];
            int c = c4 + j;
            if (!((mw >> (c & 31)) & 1u)) { ys[j] = xx; continue; }
            int rid = run_of(rs, row_off, r, c);
            int root = lfindm(parent, rid);
            float a = (float)(((unsigned)parent[root] >> 16) + 1u);
            ys[j] = powf(xx, 1.0f / sqrtf(a));
        }
        dst4[i] = make_float4(ys[0], ys[1], ys[2], ys[3]);
    }
}

extern "C" void kernel_launch(void* const* d_in, const int* in_sizes, int n_in,
                              void* d_out, int out_size, void* d_ws, size_t ws_size,
                              hipStream_t stream) {
    const float* att = (const float*)d_in[0];
    float* out = (float*)d_out;
    (void)in_sizes; (void)n_in; (void)out_size; (void)d_ws; (void)ws_size;

    k_fused<<<BATCH, 1024, 0, stream>>>(att, out);
}

// Round 26
// 127.685 us; speedup vs baseline: 5.2403x; 1.4636x over previous
//
#include <hip/hip_runtime.h>
#include <math.h>

#define BATCH 64
#define HH 256
#define WW 256
#define HW 65536            // 256*256 pixels per image
#define NPIX (BATCH * HW)   // 4194304
#define NBINS 50
#define SENT_P 0x7FFFFFFF   // background marker

#define TW 64
#define TH 32
#define TN (TW * TH)        // 2048
#define TILES_X (WW / TW)   // 4
#define TILES_PER_IMG 32
#define EDGES_PER_IMG 2560  // 3*256 vertical + 7*256 horizontal
#define BLOCKS_EDGE 10      // 2560 / 256
#define LIST_STRIDE 32768
#define CHUNKS 8            // hist chunks/image

__device__ __forceinline__ int aload(const int* p) {
    return __hip_atomic_load(p, __ATOMIC_RELAXED, __HIP_MEMORY_SCOPE_AGENT);
}
__device__ __forceinline__ void astore(int* p, int v) {
    __hip_atomic_store(p, v, __ATOMIC_RELAXED, __HIP_MEMORY_SCOPE_AGENT);
}

__device__ __forceinline__ int runstart64(unsigned long long m, int c) {
    unsigned long long sh = (~m) << (63 - c);
    return sh ? (c - __clzll(sh) + 1) : 0;
}
__device__ __forceinline__ int runlen64(unsigned long long m, int c) {
    unsigned long long sh = ~(m >> c);
    return sh ? (__ffsll(sh) - 1) : 64;
}
// wave argmax: max val, tie -> min idx (== np first-occurrence)
__device__ __forceinline__ void wave_argmax(int& bv, int& bi) {
#pragma unroll
    for (int off = 32; off > 0; off >>= 1) {
        int ov = __shfl_xor(bv, off);
        int oi = __shfl_xor(bi, off);
        if (ov > bv || (ov == bv && oi < bi)) { bv = ov; bi = oi; }
    }
}

// ---- K1: histogram partials (8 blocks/image) + zero per-image counters ----
__global__ void k_hist(const float* __restrict__ att, int* __restrict__ histp,
                       int* __restrict__ rootcnt, int* __restrict__ donecnt) {
    __shared__ int h[NBINS];
    const int b = blockIdx.y, c = blockIdx.x, t = threadIdx.x;
    if (c == 0 && t == 0) { rootcnt[b] = 0; donecnt[b] = 0; }
    if (t < NBINS) h[t] = 0;
    __syncthreads();
    const float4* src = (const float4*)(att + (size_t)b * HW) + c * 2048;
    for (int i = t; i < 2048; i += 256) {
        float4 v = src[i];
        atomicAdd(&h[min((int)(v.x * 50.0f), 49)], 1);
        atomicAdd(&h[min((int)(v.y * 50.0f), 49)], 1);
        atomicAdd(&h[min((int)(v.z * 50.0f), 49)], 1);
        atomicAdd(&h[min((int)(v.w * 50.0f), 49)], 1);
    }
    __syncthreads();
    if (t < NBINS) histp[(b * CHUNKS + c) * 64 + t] = h[t];
}

// ---- LDS union-find over run-start nodes ----
__device__ __forceinline__ int lfind(int* lp, int x) {
    int p = lp[x];
    while (p != x) { int gp = lp[p]; if (gp != p) lp[x] = gp; x = gp; p = lp[x]; }
    return x;
}
__device__ __forceinline__ void lunite(int* lp, int a, int b) {
    int ra = lfind(lp, a), rb = lfind(lp, b);
    while (ra != rb) {
        int lo = min(ra, rb), hi = max(ra, rb);
        int old = atomicMin(&lp[hi], lo);
        if (old == hi) return;
        ra = lfind(lp, lo); rb = lfind(lp, old);
    }
}
__device__ __forceinline__ int lfindm(int* lp, int x) {
    while (true) {
        int p = lp[x] & 0xFFFF;
        if (p == x) return x;
        int gp = lp[p] & 0xFFFF;
        if (gp != p) lp[x] = gp;
        x = gp;
    }
}

// ---- K2: fused threshold + run-based tile CC (R21-proven) ----
__global__ __launch_bounds__(256)
void k_init_cc(const float* __restrict__ att, const int* __restrict__ histp,
               int* parent, int* cnt, int* list, int* rootcnt) {
    __shared__ int lp[TN];
    __shared__ unsigned int msk32[TH * 2];
    const int tile = blockIdx.x;
    const int b = blockIdx.y;
    const int t = threadIdx.x;
    const int ln = t & 63, wv = t >> 6;
    const int tr0 = (tile / TILES_X) * TH;
    const int tc0 = (tile % TILES_X) * TW;
    const float* A = att + (size_t)b * HW;

    // Phase 0: per-wave inline threshold (R11-proven f64 semantics)
    int h_ln = 0;
    if (ln < NBINS)
        for (int c = 0; c < CHUNKS; ++c) h_ln += histp[(b * CHUNKS + c) * 64 + ln];
    int bv = (ln < NBINS) ? h_ln : -1, bi = ln;
    wave_argmax(bv, bi);
    const int ind_max = bi;
    int bv2 = (ln < NBINS && ln > ind_max) ? h_ln : -1, bi2 = ln;
    wave_argmax(bv2, bi2);
    const double tv = (double)bi2 / 50.0;

    if (t < TH * 2) msk32[t] = 0;
    __syncthreads();

    // Phase 1: vectorized fg -> nibble atomicOr into row masks
    for (int i = t; i < TN / 4; i += 256) {
        int r = i >> 4, c4 = (i & 15) * 4;
        float4 v = *(const float4*)(A + (tr0 + r) * WW + tc0 + c4);
        unsigned nib = (((double)v.x > tv) ? 1u : 0u)
                     | (((double)v.y > tv) ? 2u : 0u)
                     | (((double)v.z > tv) ? 4u : 0u)
                     | (((double)v.w > tv) ? 8u : 0u);
        if (nib) atomicOr(&msk32[r * 2 + (c4 >> 5)], nib << (c4 & 31));
    }
    __syncthreads();

    // Phase 1b: init lp at run starts
    for (int k = 0; k < TH / 4; ++k) {
        int r = wv + 4 * k;
        unsigned long long m = (unsigned long long)msk32[r * 2]
                             | ((unsigned long long)msk32[r * 2 + 1] << 32);
        if (((m >> ln) & 1ull) && (ln == 0 || !((m >> (ln - 1)) & 1ull)))
            lp[r * TW + ln] = r * TW + ln;
    }
    __syncthreads();

    // Phase 2: vertical unions, one per overlap segment
    for (int k = 0; k < TH / 4; ++k) {
        int r = wv + 4 * k;
        if (r >= TH - 1) continue;
        unsigned long long m0 = (unsigned long long)msk32[r * 2]
                              | ((unsigned long long)msk32[r * 2 + 1] << 32);
        unsigned long long m1 = (unsigned long long)msk32[(r + 1) * 2]
                              | ((unsigned long long)msk32[(r + 1) * 2 + 1] << 32);
        unsigned long long ov = m0 & m1;
        if (((ov >> ln) & 1ull) && (ln == 0 || !((ov >> (ln - 1)) & 1ull)))
            lunite(lp, r * TW + runstart64(m0, ln),
                       (r + 1) * TW + runstart64(m1, ln));
    }
    __syncthreads();

    // Phase 3: deposit run lengths at local roots
    for (int k = 0; k < TH / 4; ++k) {
        int r = wv + 4 * k;
        unsigned long long m = (unsigned long long)msk32[r * 2]
                             | ((unsigned long long)msk32[r * 2 + 1] << 32);
        if (((m >> ln) & 1ull) && (ln == 0 || !((m >> (ln - 1)) & 1ull))) {
            int L = runlen64(m, ln);
            int root = lfindm(lp, r * TW + ln);
            atomicAdd(&lp[root], L << 16);
        }
    }
    __syncthreads();

    // Phase 4: write PURE parent; roots zero cnt + append (groot,size-1) to list
    int* P = parent + (size_t)b * HW;
    for (int i = t; i < TN / 4; i += 256) {
        int r = i >> 4, c4 = (i & 15) * 4;
        unsigned long long m = (unsigned long long)msk32[r * 2]
                             | ((unsigned long long)msk32[r * 2 + 1] << 32);
        int w[4];
#pragma unroll
        for (int j = 0; j < 4; ++j) {
            int c = c4 + j, l = r * TW + c;
            if (!((m >> c) & 1ull)) { w[j] = SENT_P; continue; }
            int node = r * TW + runstart64(m, c);
            int root = lfindm(lp, node);
            int groot = (tr0 + (root >> 6)) * WW + tc0 + (root & (TW - 1));
            w[j] = groot;
            if (l == root) {
                int size = lp[root] >> 16;             // 1..2048
                cnt[(size_t)b * HW + groot] = 0;
                int idx = atomicAdd(&rootcnt[b], 1);
                list[b * LIST_STRIDE + idx] = groot | ((size - 1) << 16);
            }
        }
        *(int4*)(P + (tr0 + r) * WW + tc0 + c4) = make_int4(w[0], w[1], w[2], w[3]);
    }
}

// ---- global union-find (agent-scope, R14-proven) ----
__device__ __forceinline__ int findroot_h(int* P, int x) {
    int p = aload(P + x);
    while (p != x) {
        int gp = aload(P + p);
        astore(P + x, gp);
        x = gp; p = aload(P + x);
    }
    return x;
}
__device__ __forceinline__ void unite(int* P, int a, int b) {
    int ra = findroot_h(P, a);
    int rb = findroot_h(P, b);
    while (ra != rb) {
        int lo = min(ra, rb), hi = max(ra, rb);
        int old = atomicMin(&P[hi], lo);
        if (old == hi) return;
        ra = findroot_h(P, lo);
        rb = findroot_h(P, old);
    }
}

// ---- K3: boundary merge + (last block per image) accumulate ----
// Each of the 10 edge-blocks/image does exactly 1 edge/thread (all agent-scope
// ops -> at the coherent point when done), fences, bumps donecnt. The last
// block inherits the LIGHT tail: rootcnt[b] list entries / 256 threads, each a
// short aload walk + one fire-and-forget atomicAdd. (R23's mistake was
// serializing the 2560 UNIONS into one block; here unions stay 10-way parallel.)
__global__ __launch_bounds__(256)
void k_bmerge_acc(int* parent, int* cnt, const int* __restrict__ list,
                  const int* __restrict__ rootcnt, int* donecnt) {
    __shared__ int s_last;
    const int b = blockIdx.x / BLOCKS_EDGE;
    const int blk = blockIdx.x % BLOCKS_EDGE;
    const int t = threadIdx.x;
    int* P = parent + (size_t)b * HW;

    int e = blk * 256 + t;                 // 0..2559, exactly one edge per thread
    int l, m;
    if (e < 768) {                         // vertical: cols {63,127,191}
        int k = e / 256, row = e & 255;
        l = row * WW + (TW - 1 + TW * k); m = l + 1;
    } else {                               // horizontal: rows {31,63,...,223}
        int e2 = e - 768;
        int k = e2 / 256, col = e2 & 255;
        l = (TH - 1 + TH * k) * WW + col; m = l + WW;
    }
    if (aload(P + l) != SENT_P && aload(P + m) != SENT_P) unite(P, l, m);

    __threadfence();
    __syncthreads();
    if (t == 0)
        s_last = (atomicAdd(&donecnt[b], 1) == BLOCKS_EDGE - 1) ? 1 : 0;
    __syncthreads();
    if (!s_last) return;

    // all unions of image b complete & visible at coherent point; aload bypasses caches
    int n = aload(&rootcnt[b]);
    for (int i = t; i < n; i += 256) {
        int ent = aload(&list[b * LIST_STRIDE + i]);
        int xi = ent & 0xFFFF;
        int size = (ent >> 16) + 1;
        int p = aload(P + xi);
        while (p != xi) { xi = p; p = aload(P + xi); }
        atomicAdd(&cnt[(size_t)b * HW + xi], size);
    }
}

// ---- K4: finalize — plain L1-hot walk + cnt lookup; hw exp2/log2 pow ----
__global__ void k_final(const float* __restrict__ att, const int* __restrict__ parent,
                        const int* __restrict__ cnt, float* __restrict__ out) {
    int g = blockIdx.x * blockDim.x + threadIdx.x;
    int base = g * 4;
    if (base >= NPIX) return;
    const int* P = parent + (base & ~(HW - 1));
    const int* C = cnt + (base & ~(HW - 1));
    float4 v = ((const float4*)att)[g];
    int4 pv = ((const int4*)parent)[g];
    int vv[4] = {pv.x, pv.y, pv.z, pv.w};
    float xs[4] = {v.x, v.y, v.z, v.w};
    float ys[4];
#pragma unroll
    for (int j = 0; j < 4; ++j) {
        float x = xs[j];
        int w = vv[j];
        if (w == SENT_P) { ys[j] = x; continue; }
        int xi = w, p = P[xi];
        while (p != xi) { xi = p; p = P[xi]; }     // depth ~1-2
        int a = C[xi];
        if (a <= 1) { ys[j] = x; continue; }       // x^1 == x
        float e = 1.0f / sqrtf((float)a);
        // x > thr >= 0 here; v_log_f32/v_exp_f32: |err| ~ |log2 x|*ulp << 2e-2
        ys[j] = __builtin_amdgcn_exp2f(e * __builtin_amdgcn_logf(x));
    }
    ((float4*)out)[g] = make_float4(ys[0], ys[1], ys[2], ys[3]);
}

// ================= tiny-ws fallback: R11-proven monolith =================
__global__ __launch_bounds__(1024)
void k_all(const float* __restrict__ att, float* out) {
    const int b = blockIdx.x;
    const int t = threadIdx.x;
    const float* A = att + (size_t)b * HW;
    int* L = (int*)out + (size_t)b * HW;
    __shared__ int hist[NBINS];
    __shared__ double s_thr;
    __shared__ int s_changed;
    for (int i = t; i < NBINS; i += 1024) hist[i] = 0;
    if (t == 0) s_changed = 0;
    __syncthreads();
    const float4* src4 = (const float4*)A;
    for (int i = t; i < HW / 4; i += 1024) {
        float4 v = src4[i];
        atomicAdd(&hist[min((int)(v.x * 50.0f), 49)], 1);
        atomicAdd(&hist[min((int)(v.y * 50.0f), 49)], 1);
        atomicAdd(&hist[min((int)(v.z * 50.0f), 49)], 1);
        atomicAdd(&hist[min((int)(v.w * 50.0f), 49)], 1);
    }
    __syncthreads();
    if (t == 0) {
        int ind_max = 0, bv = hist[0];
        for (int j = 1; j < NBINS; ++j)
            if (hist[j] > bv) { bv = hist[j]; ind_max = j; }
        int ind_sec = 0, bv2 = -1;
        for (int j = 1; j < NBINS; ++j) {
            int v = (j > ind_max) ? hist[j] : -1;
            if (v > bv2) { bv2 = v; ind_sec = j; }
        }
        s_thr = (double)ind_sec / 50.0;
    }
    __syncthreads();
    const double tv = s_thr;
    for (int i = t; i < HW / 4; i += 1024) {
        float4 v = src4[i];
        int l = i * 4;
        astore(L + l + 0, ((double)v.x > tv) ? (l + 0) : SENT_P);
        astore(L + l + 1, ((double)v.y > tv) ? (l + 1) : SENT_P);
        astore(L + l + 2, ((double)v.z > tv) ? (l + 2) : SENT_P);
        astore(L + l + 3, ((double)v.w > tv) ? (l + 3) : SENT_P);
    }
    __syncthreads();
    for (;;) {
        int changed = 0;
        for (int p = t; p < HW; p += 1024) {
            int v = aload(L + p);
            if (v == SENT_P) continue;
            int m = v;
            int col = p & (WW - 1), row = p >> 8;
            if (col > 0)      m = min(m, aload(L + p - 1));
            if (col < WW - 1) m = min(m, aload(L + p + 1));
            if (row > 0)      m = min(m, aload(L + p - WW));
            if (row < HH - 1) m = min(m, aload(L + p + WW));
            m = min(m, aload(L + m));
            if (m < v) { astore(L + p, m); changed = 1; }
        }
        if (changed) s_changed = 1;
        __syncthreads();
        int ch = s_changed;
        __syncthreads();
        if (!ch) break;
        if (t == 0) s_changed = 0;
        __syncthreads();
    }
    for (int p = t; p < HW; p += 1024) {
        int v = aload(L + p);
        if (v == SENT_P) continue;
        int lo = v & 0xFFFF;
        if (lo != p) atomicAdd((unsigned int*)(L + lo), 0x10000u);
    }
    __syncthreads();
    for (int p = t; p < HW; p += 1024) {
        int v = aload(L + p);
        if (v == SENT_P) continue;
        int lo = v & 0xFFFF;
        if (lo != p) astore(L + p, aload(L + lo));
    }
    __syncthreads();
    for (int p = t; p < HW; p += 1024) {
        float x = A[p];
        unsigned v = (unsigned)aload(L + p);
        float y = x;
        if (v != (unsigned)SENT_P) {
            float a = (float)((v >> 16) + 1u);
            y = powf(x, 1.0f / sqrtf(a));
        }
        out[(size_t)b * HW + p] = y;
    }
}

extern "C" void kernel_launch(void* const* d_in, const int* in_sizes, int n_in,
                              void* d_out, int out_size, void* d_ws, size_t ws_size,
                              hipStream_t stream) {
    const float* att = (const float*)d_in[0];
    float* out = (float*)d_out;
    (void)in_sizes; (void)n_in; (void)out_size;

    const size_t PAR_B  = (size_t)NPIX * 4;                    // 16 MB
    const size_t CNT_B  = (size_t)NPIX * 4;                    // 16 MB
    const size_t LIST_B = (size_t)BATCH * LIST_STRIDE * 4;     // 8 MB
    const size_t HIST_B = (size_t)BATCH * CHUNKS * 64 * 4;     // 128 KB
    if (ws_size < PAR_B + CNT_B + LIST_B + HIST_B + 2048) {
        k_all<<<BATCH, 1024, 0, stream>>>(att, out);           // proven fallback
        return;
    }
    int* parent  = (int*)d_ws;
    int* cnt     = (int*)((char*)d_ws + PAR_B);
    int* list    = (int*)((char*)d_ws + PAR_B + CNT_B);
    int* histp   = (int*)((char*)d_ws + PAR_B + CNT_B + LIST_B);
    int* rootcnt = (int*)((char*)d_ws + PAR_B + CNT_B + LIST_B + HIST_B);
    int* donecnt = rootcnt + BATCH;

    k_hist<<<dim3(CHUNKS, BATCH), 256, 0, stream>>>(att, histp, rootcnt, donecnt);
    k_init_cc<<<dim3(TILES_PER_IMG, BATCH), 256, 0, stream>>>(att, histp, parent,
                                                              cnt, list, rootcnt);
    k_bmerge_acc<<<BATCH * BLOCKS_EDGE, 256, 0, stream>>>(parent, cnt, list,
                                                          rootcnt, donecnt);
    k_final<<<NPIX / (256 * 4), 256, 0, stream>>>(att, parent, cnt, out);
}

// Round 27
// 85.819 us; speedup vs baseline: 7.7968x; 1.4879x over previous
//
#include <hip/hip_runtime.h>
#include <math.h>

#define BATCH 64
#define HH 256
#define WW 256
#define HW 65536            // 256*256 pixels per image
#define NPIX (BATCH * HW)   // 4194304
#define NBINS 50
#define SENT_P 0x7FFFFFFF   // background marker

#define TW 64
#define TH 64
#define TN (TW * TH)
#define TILES_X (WW / TW)   // 4
#define TILES_PER_IMG 16
#define LIST_STRIDE 32768   // max tile-roots per image

__device__ __forceinline__ int aload(const int* p) {
    return __hip_atomic_load(p, __ATOMIC_RELAXED, __HIP_MEMORY_SCOPE_AGENT);
}
__device__ __forceinline__ void astore(int* p, int v) {
    __hip_atomic_store(p, v, __ATOMIC_RELAXED, __HIP_MEMORY_SCOPE_AGENT);
}

__device__ __forceinline__ int runstart64(unsigned long long m, int c) {
    unsigned long long sh = (~m) << (63 - c);
    return sh ? (c - __clzll(sh) + 1) : 0;
}
__device__ __forceinline__ int runlen64(unsigned long long m, int c) {
    unsigned long long sh = ~(m >> c);
    return sh ? (__ffsll(sh) - 1) : 64;
}
// wave argmax: max val, tie -> min idx (== np first-occurrence)
__device__ __forceinline__ void wave_argmax(int& bv, int& bi) {
#pragma unroll
    for (int off = 32; off > 0; off >>= 1) {
        int ov = __shfl_xor(bv, off);
        int oi = __shfl_xor(bi, off);
        if (ov > bv || (ov == bv && oi < bi)) { bv = ov; bi = oi; }
    }
}

// ---- K1: histogram partials (8 blocks/image) + zero per-image root counter ----
__global__ void k_hist(const float* __restrict__ att, int* __restrict__ histp,
                       int* __restrict__ rootcnt) {
    __shared__ int h[NBINS];
    const int b = blockIdx.y, c = blockIdx.x, t = threadIdx.x;
    if (c == 0 && t == 0) rootcnt[b] = 0;       // published at kernel boundary
    if (t < NBINS) h[t] = 0;
    __syncthreads();
    const float4* src = (const float4*)(att + (size_t)b * HW) + c * 2048;
    for (int i = t; i < 2048; i += 256) {
        float4 v = src[i];
        atomicAdd(&h[min((int)(v.x * 50.0f), 49)], 1);
        atomicAdd(&h[min((int)(v.y * 50.0f), 49)], 1);
        atomicAdd(&h[min((int)(v.z * 50.0f), 49)], 1);
        atomicAdd(&h[min((int)(v.w * 50.0f), 49)], 1);
    }
    __syncthreads();
    if (t < NBINS) histp[(b * 8 + c) * 64 + t] = h[t];
}

// ---- LDS union-find over run-start nodes ----
__device__ __forceinline__ void lunite(int* lp, int a, int b) {
    int x = a, p = lp[x];
    while (p != x) { int gp = lp[p]; if (gp != p) lp[x] = gp; x = gp; p = lp[x]; }
    int ra = x;
    x = b; p = lp[x];
    while (p != x) { int gp = lp[p]; if (gp != p) lp[x] = gp; x = gp; p = lp[x]; }
    int rb = x;
    while (ra != rb) {
        int lo = min(ra, rb), hi = max(ra, rb);
        int old = atomicMin(&lp[hi], lo);
        if (old == hi) return;
        x = lo; p = lp[x];
        while (p != x) { int gp = lp[p]; if (gp != p) lp[x] = gp; x = gp; p = lp[x]; }
        ra = x;
        x = old; p = lp[x];
        while (p != x) { int gp = lp[p]; if (gp != p) lp[x] = gp; x = gp; p = lp[x]; }
        rb = x;
    }
}
// masked find (after length deposits: root slots carry size in high bits)
__device__ __forceinline__ int lfindm(int* lp, int x) {
    while (true) {
        int p = lp[x] & 0xFFFF;
        if (p == x) return x;
        int gp = lp[p] & 0xFFFF;
        if (gp != p) lp[x] = gp;
        x = gp;
    }
}

// ---- K2: fused threshold + run-based tile CC; PURE parent + cnt/list out ----
__global__ __launch_bounds__(256)
void k_init_cc(const float* __restrict__ att, const int* __restrict__ histp,
               int* parent, int* __restrict__ cnt, int* __restrict__ list,
               int* __restrict__ rootcnt) {
    __shared__ int lp[TN];
    __shared__ unsigned long long msk[TH];
    const int tile = blockIdx.x;
    const int b = blockIdx.y;
    const int t = threadIdx.x;
    const int wv = t >> 6, ln = t & 63;
    const int tr0 = (tile / TILES_X) * TH;
    const int tc0 = (tile % TILES_X) * TW;
    const float* A = att + (size_t)b * HW;

    // Phase 0: per-wave inline threshold (R11-proven f64 semantics)
    int h_ln = 0;
    if (ln < NBINS)
        for (int c = 0; c < 8; ++c) h_ln += histp[(b * 8 + c) * 64 + ln];
    int bv = (ln < NBINS) ? h_ln : -1, bi = ln;
    wave_argmax(bv, bi);
    const int ind_max = bi;
    int bv2 = (ln < NBINS && ln > ind_max) ? h_ln : -1, bi2 = ln;
    wave_argmax(bv2, bi2);
    const double tv = (double)bi2 / 50.0;

    // Phase 1: row masks + lp init at run starts
    for (int k = 0; k < 16; ++k) {
        int r = wv + 4 * k;
        float x = A[(tr0 + r) * WW + tc0 + ln];
        bool fg = (double)x > tv;
        unsigned long long m = __ballot(fg);
        if (ln == 0) msk[r] = m;
        if (fg && (ln == 0 || !((m >> (ln - 1)) & 1ull)))
            lp[r * TW + ln] = r * TW + ln;
    }
    __syncthreads();

    // Phase 2: vertical unions, one per overlap segment
    for (int k = 0; k < 16; ++k) {
        int r = wv + 4 * k;
        if (r >= TH - 1) continue;
        unsigned long long m0 = msk[r], m1 = msk[r + 1];
        unsigned long long ov = m0 & m1;
        if (((ov >> ln) & 1ull) && (ln == 0 || !((ov >> (ln - 1)) & 1ull)))
            lunite(lp, r * TW + runstart64(m0, ln),
                       (r + 1) * TW + runstart64(m1, ln));
    }
    __syncthreads();

    // Phase 3: deposit run lengths at local roots
    for (int k = 0; k < 16; ++k) {
        int r = wv + 4 * k;
        unsigned long long m = msk[r];
        if (((m >> ln) & 1ull) && (ln == 0 || !((m >> (ln - 1)) & 1ull))) {
            int L = runlen64(m, ln);
            int root = lfindm(lp, r * TW + ln);
            atomicAdd(&lp[root], L << 16);
        }
    }
    __syncthreads();

    // Phase 4: write PURE parent; roots also zero cnt + append (groot,size) to list
    int* P = parent + (size_t)b * HW;
    for (int i = t; i < TN / 4; i += 256) {
        int r = i >> 4, c4 = (i & 15) * 4;
        unsigned long long m = msk[r];
        int w[4];
#pragma unroll
        for (int j = 0; j < 4; ++j) {
            int c = c4 + j, l = r * TW + c;
            if (!((m >> c) & 1ull)) { w[j] = SENT_P; continue; }
            int node = r * TW + runstart64(m, c);
            int root = lfindm(lp, node);
            int groot = (tr0 + (root >> 6)) * WW + tc0 + (root & (TW - 1));
            w[j] = groot;                              // PURE (root -> self)
            if (l == root) {
                int size = lp[root] >> 16;             // 1..4096
                cnt[(size_t)b * HW + groot] = 0;       // zero-init (plain)
                int idx = atomicAdd(&rootcnt[b], 1);
                list[b * LIST_STRIDE + idx] = groot | ((size - 1) << 16);
            }
        }
        *(int4*)(P + (tr0 + r) * WW + tc0 + c4) = make_int4(w[0], w[1], w[2], w[3]);
    }
}

// ---- K3: boundary merge — PURE atomicMin linking (R14-proven) ----
__device__ __forceinline__ int findroot_h(int* P, int x) {
    int p = aload(P + x);
    while (p != x) {
        int gp = aload(P + p);
        astore(P + x, gp);
        x = gp; p = aload(P + x);
    }
    return x;
}
__device__ __forceinline__ void unite(int* P, int a, int b) {
    int ra = findroot_h(P, a);
    int rb = findroot_h(P, b);
    while (ra != rb) {
        int lo = min(ra, rb), hi = max(ra, rb);
        int old = atomicMin(&P[hi], lo);
        if (old == hi) return;
        ra = findroot_h(P, lo);
        rb = findroot_h(P, old);
    }
}
__global__ void k_bmerge(int* parent) {
    int g = blockIdx.x * blockDim.x + threadIdx.x;
    if (g >= BATCH * 1536) return;
    int b = g / 1536, e = g % 1536;
    int* P = parent + (size_t)b * HW;
    int l, m;
    if (e < 768) {          // vertical edges: cols {63,127,191}
        int k = e / 256, row = e & 255;
        l = row * WW + (TW - 1 + TW * k); m = l + 1;
    } else {                // horizontal edges: rows {63,127,191}
        int e2 = e - 768;
        int k = e2 / 256, col = e2 & 255;
        l = (TH - 1 + TH * k) * WW + col; m = l + WW;
    }
    if (aload(P + l) != SENT_P && aload(P + m) != SENT_P) unite(P, l, m);
}

// ---- K4: accumulate — one thread per tile root: walk frozen parent, one add ----
__global__ void k_acc(const int* __restrict__ parent, int* __restrict__ cnt,
                      const int* __restrict__ list, const int* __restrict__ rootcnt) {
    int g = blockIdx.x * blockDim.x + threadIdx.x;
    int b = g / LIST_STRIDE, i = g - b * LIST_STRIDE;
    if (b >= BATCH || i >= rootcnt[b]) return;
    int e = list[b * LIST_STRIDE + i];
    int x = e & 0xFFFF;
    int size = (e >> 16) + 1;
    const int* P = parent + (size_t)b * HW;
    int p = P[x];                              // plain loads: topology frozen
    while (p != x) { x = p; p = P[x]; }
    atomicAdd(&cnt[(size_t)b * HW + x], size); // fire-and-forget, memory-side
}

// ---- K5: finalize — plain L1-hot walk + cnt lookup; hw exp2/log2 pow ----
__global__ void k_final(const float* __restrict__ att, const int* __restrict__ parent,
                        const int* __restrict__ cnt, float* __restrict__ out) {
    int g = blockIdx.x * blockDim.x + threadIdx.x;
    int base = g * 4;
    if (base >= NPIX) return;
    const int* P = parent + (base & ~(HW - 1));
    const int* C = cnt + (base & ~(HW - 1));
    float4 v = ((const float4*)att)[g];
    int4 pv = ((const int4*)parent)[g];
    int vv[4] = {pv.x, pv.y, pv.z, pv.w};
    float xs[4] = {v.x, v.y, v.z, v.w};
    float ys[4];
#pragma unroll
    for (int j = 0; j < 4; ++j) {
        float x = xs[j];
        int w = vv[j];
        if (w == SENT_P) { ys[j] = x; continue; }
        int xi = w, p = P[xi];
        while (p != xi) { xi = p; p = P[xi]; }     // depth ~1-2 post-halving
        int a = C[xi];
        if (a <= 1) { ys[j] = x; continue; }       // x^1 == x
        float e = 1.0f / sqrtf((float)a);
        // x > thr >= 0 here; v_log_f32/v_exp_f32: |err| ~ |log2 x|*ulp << 2e-2
        ys[j] = __builtin_amdgcn_exp2f(e * __builtin_amdgcn_logf(x));
    }
    ((float4*)out)[g] = make_float4(ys[0], ys[1], ys[2], ys[3]);
}

// ================= fallback (tiny ws): R11-proven monolith =================
__global__ __launch_bounds__(1024)
void k_all(const float* __restrict__ att, float* out) {
    const int b = blockIdx.x;
    const int t = threadIdx.x;
    const float* A = att + (size_t)b * HW;
    int* L = (int*)out + (size_t)b * HW;
    __shared__ int hist[NBINS];
    __shared__ double s_thr;
    __shared__ int s_changed;
    for (int i = t; i < NBINS; i += 1024) hist[i] = 0;
    if (t == 0) s_changed = 0;
    __syncthreads();
    const float4* src4 = (const float4*)A;
    for (int i = t; i < HW / 4; i += 1024) {
        float4 v = src4[i];
        atomicAdd(&hist[min((int)(v.x * 50.0f), 49)], 1);
        atomicAdd(&hist[min((int)(v.y * 50.0f), 49)], 1);
        atomicAdd(&hist[min((int)(v.z * 50.0f), 49)], 1);
        atomicAdd(&hist[min((int)(v.w * 50.0f), 49)], 1);
    }
    __syncthreads();
    if (t == 0) {
        int ind_max = 0, bv = hist[0];
        for (int j = 1; j < NBINS; ++j)
            if (hist[j] > bv) { bv = hist[j]; ind_max = j; }
        int ind_sec = 0, bv2 = -1;
        for (int j = 1; j < NBINS; ++j) {
            int v = (j > ind_max) ? hist[j] : -1;
            if (v > bv2) { bv2 = v; ind_sec = j; }
        }
        s_thr = (double)ind_sec / 50.0;
    }
    __syncthreads();
    const double tv = s_thr;
    for (int i = t; i < HW / 4; i += 1024) {
        float4 v = src4[i];
        int l = i * 4;
        astore(L + l + 0, ((double)v.x > tv) ? (l + 0) : SENT_P);
        astore(L + l + 1, ((double)v.y > tv) ? (l + 1) : SENT_P);
        astore(L + l + 2, ((double)v.z > tv) ? (l + 2) : SENT_P);
        astore(L + l + 3, ((double)v.w > tv) ? (l + 3) : SENT_P);
    }
    __syncthreads();
    for (;;) {
        int changed = 0;
        for (int p = t; p < HW; p += 1024) {
            int v = aload(L + p);
            if (v == SENT_P) continue;
            int m = v;
            int col = p & (WW - 1), row = p >> 8;
            if (col > 0)      m = min(m, aload(L + p - 1));
            if (col < WW - 1) m = min(m, aload(L + p + 1));
            if (row > 0)      m = min(m, aload(L + p - WW));
            if (row < HH - 1) m = min(m, aload(L + p + WW));
            m = min(m, aload(L + m));
            if (m < v) { astore(L + p, m); changed = 1; }
        }
        if (changed) s_changed = 1;
        __syncthreads();
        int ch = s_changed;
        __syncthreads();
        if (!ch) break;
        if (t == 0) s_changed = 0;
        __syncthreads();
    }
    for (int p = t; p < HW; p += 1024) {
        int v = aload(L + p);
        if (v == SENT_P) continue;
        int lo = v & 0xFFFF;
        if (lo != p) atomicAdd((unsigned int*)(L + lo), 0x10000u);
    }
    __syncthreads();
    for (int p = t; p < HW; p += 1024) {
        int v = aload(L + p);
        if (v == SENT_P) continue;
        int lo = v & 0xFFFF;
        if (lo != p) astore(L + p, aload(L + lo));
    }
    __syncthreads();
    for (int p = t; p < HW; p += 1024) {
        float x = A[p];
        unsigned v = (unsigned)aload(L + p);
        float y = x;
        if (v != (unsigned)SENT_P) {
            float a = (float)((v >> 16) + 1u);
            y = powf(x, 1.0f / sqrtf(a));
        }
        out[(size_t)b * HW + p] = y;
    }
}

extern "C" void kernel_launch(void* const* d_in, const int* in_sizes, int n_in,
                              void* d_out, int out_size, void* d_ws, size_t ws_size,
                              hipStream_t stream) {
    const float* att = (const float*)d_in[0];
    float* out = (float*)d_out;
    (void)in_sizes; (void)n_in; (void)out_size;

    const size_t PAR_B  = (size_t)NPIX * 4;                 // 16 MB
    const size_t CNT_B  = (size_t)NPIX * 4;                 // 16 MB
    const size_t LIST_B = (size_t)BATCH * LIST_STRIDE * 4;  // 8 MB
    const size_t HIST_B = (size_t)BATCH * 8 * 64 * 4;       // 128 KB
    if (ws_size < PAR_B + CNT_B + LIST_B + HIST_B + 1024) {
        k_all<<<BATCH, 1024, 0, stream>>>(att, out);        // proven fallback
        return;
    }
    int* parent  = (int*)d_ws;
    int* cnt     = (int*)((char*)d_ws + PAR_B);
    int* list    = (int*)((char*)d_ws + PAR_B + CNT_B);
    int* histp   = (int*)((char*)d_ws + PAR_B + CNT_B + LIST_B);
    int* rootcnt = (int*)((char*)d_ws + PAR_B + CNT_B + LIST_B + HIST_B);

    k_hist<<<dim3(8, BATCH), 256, 0, stream>>>(att, histp, rootcnt);
    k_init_cc<<<dim3(TILES_PER_IMG, BATCH), 256, 0, stream>>>(att, histp, parent,
                                                              cnt, list, rootcnt);
    k_bmerge<<<(BATCH * 1536 + 255) / 256, 256, 0, stream>>>(parent);
    k_acc<<<(BATCH * LIST_STRIDE) / 256, 256, 0, stream>>>(parent, cnt, list, rootcnt);
    k_final<<<NPIX / (256 * 4), 256, 0, stream>>>(att, parent, cnt, out);
}

// Round 28
// 83.707 us; speedup vs baseline: 7.9935x; 1.0252x over previous
//
#include <hip/hip_runtime.h>
#include <math.h>

#define BATCH 64
#define HH 256
#define WW 256
#define HW 65536            // 256*256 pixels per image
#define NPIX (BATCH * HW)   // 4194304
#define NBINS 50
#define SENT_P 0x7FFFFFFF   // background marker

#define TW 64
#define TH 64
#define TN (TW * TH)
#define TILES_X (WW / TW)   // 4
#define TILES_PER_IMG 16
#define LIST_STRIDE 32768   // max tile-roots per image

__device__ __forceinline__ int aload(const int* p) {
    return __hip_atomic_load(p, __ATOMIC_RELAXED, __HIP_MEMORY_SCOPE_AGENT);
}
__device__ __forceinline__ void astore(int* p, int v) {
    __hip_atomic_store(p, v, __ATOMIC_RELAXED, __HIP_MEMORY_SCOPE_AGENT);
}

__device__ __forceinline__ int runstart64(unsigned long long m, int c) {
    unsigned long long sh = (~m) << (63 - c);
    return sh ? (c - __clzll(sh) + 1) : 0;
}
__device__ __forceinline__ int runlen64(unsigned long long m, int c) {
    unsigned long long sh = ~(m >> c);
    return sh ? (__ffsll(sh) - 1) : 64;
}
// wave argmax: max val, tie -> min idx (== np first-occurrence)
__device__ __forceinline__ void wave_argmax(int& bv, int& bi) {
#pragma unroll
    for (int off = 32; off > 0; off >>= 1) {
        int ov = __shfl_xor(bv, off);
        int oi = __shfl_xor(bi, off);
        if (ov > bv || (ov == bv && oi < bi)) { bv = ov; bi = oi; }
    }
}

// ---- K1: histogram partials (8 blocks/image) + zero per-image root counter ----
__global__ void k_hist(const float* __restrict__ att, int* __restrict__ histp,
                       int* __restrict__ rootcnt) {
    __shared__ int h[NBINS];
    const int b = blockIdx.y, c = blockIdx.x, t = threadIdx.x;
    if (c == 0 && t == 0) rootcnt[b] = 0;       // published at kernel boundary
    if (t < NBINS) h[t] = 0;
    __syncthreads();
    const float4* src = (const float4*)(att + (size_t)b * HW) + c * 2048;
    for (int i = t; i < 2048; i += 256) {
        float4 v = src[i];
        atomicAdd(&h[min((int)(v.x * 50.0f), 49)], 1);
        atomicAdd(&h[min((int)(v.y * 50.0f), 49)], 1);
        atomicAdd(&h[min((int)(v.z * 50.0f), 49)], 1);
        atomicAdd(&h[min((int)(v.w * 50.0f), 49)], 1);
    }
    __syncthreads();
    if (t < NBINS) histp[(b * 8 + c) * 64 + t] = h[t];
}

// ---- LDS union-find over run-start nodes ----
__device__ __forceinline__ void lunite(int* lp, int a, int b) {
    int x = a, p = lp[x];
    while (p != x) { int gp = lp[p]; if (gp != p) lp[x] = gp; x = gp; p = lp[x]; }
    int ra = x;
    x = b; p = lp[x];
    while (p != x) { int gp = lp[p]; if (gp != p) lp[x] = gp; x = gp; p = lp[x]; }
    int rb = x;
    while (ra != rb) {
        int lo = min(ra, rb), hi = max(ra, rb);
        int old = atomicMin(&lp[hi], lo);
        if (old == hi) return;
        x = lo; p = lp[x];
        while (p != x) { int gp = lp[p]; if (gp != p) lp[x] = gp; x = gp; p = lp[x]; }
        ra = x;
        x = old; p = lp[x];
        while (p != x) { int gp = lp[p]; if (gp != p) lp[x] = gp; x = gp; p = lp[x]; }
        rb = x;
    }
}
// masked find (after length deposits: root slots carry size in high bits)
__device__ __forceinline__ int lfindm(int* lp, int x) {
    while (true) {
        int p = lp[x] & 0xFFFF;
        if (p == x) return x;
        int gp = lp[p] & 0xFFFF;
        if (gp != p) lp[x] = gp;
        x = gp;
    }
}

// ---- K2: fused threshold + run-based tile CC (1024 threads: 4x shorter
//          serial chains per thread vs R27's 256 — phases 1-3 do 4 rows/wave,
//          phase 4 exactly 1 px-quad/thread) ----
__global__ __launch_bounds__(1024)
void k_init_cc(const float* __restrict__ att, const int* __restrict__ histp,
               int* parent, int* __restrict__ cnt, int* __restrict__ list,
               int* __restrict__ rootcnt) {
    __shared__ int lp[TN];
    __shared__ unsigned long long msk[TH];
    const int tile = blockIdx.x;
    const int b = blockIdx.y;
    const int t = threadIdx.x;
    const int wv = t >> 6, ln = t & 63;          // 16 waves
    const int tr0 = (tile / TILES_X) * TH;
    const int tc0 = (tile % TILES_X) * TW;
    const float* A = att + (size_t)b * HW;

    // Phase 0: per-wave inline threshold (R11-proven f64 semantics)
    int h_ln = 0;
    if (ln < NBINS)
        for (int c = 0; c < 8; ++c) h_ln += histp[(b * 8 + c) * 64 + ln];
    int bv = (ln < NBINS) ? h_ln : -1, bi = ln;
    wave_argmax(bv, bi);
    const int ind_max = bi;
    int bv2 = (ln < NBINS && ln > ind_max) ? h_ln : -1, bi2 = ln;
    wave_argmax(bv2, bi2);
    const double tv = (double)bi2 / 50.0;

    // Phase 1: row masks + lp init at run starts (4 rows per wave)
#pragma unroll
    for (int k = 0; k < 4; ++k) {
        int r = wv + 16 * k;
        float x = A[(tr0 + r) * WW + tc0 + ln];
        bool fg = (double)x > tv;
        unsigned long long m = __ballot(fg);
        if (ln == 0) msk[r] = m;
        if (fg && (ln == 0 || !((m >> (ln - 1)) & 1ull)))
            lp[r * TW + ln] = r * TW + ln;
    }
    __syncthreads();

    // Phase 2: vertical unions, one per overlap segment
#pragma unroll
    for (int k = 0; k < 4; ++k) {
        int r = wv + 16 * k;
        if (r >= TH - 1) continue;
        unsigned long long m0 = msk[r], m1 = msk[r + 1];
        unsigned long long ov = m0 & m1;
        if (((ov >> ln) & 1ull) && (ln == 0 || !((ov >> (ln - 1)) & 1ull)))
            lunite(lp, r * TW + runstart64(m0, ln),
                       (r + 1) * TW + runstart64(m1, ln));
    }
    __syncthreads();

    // Phase 3: deposit run lengths at local roots
#pragma unroll
    for (int k = 0; k < 4; ++k) {
        int r = wv + 16 * k;
        unsigned long long m = msk[r];
        if (((m >> ln) & 1ull) && (ln == 0 || !((m >> (ln - 1)) & 1ull))) {
            int L = runlen64(m, ln);
            int root = lfindm(lp, r * TW + ln);
            atomicAdd(&lp[root], L << 16);
        }
    }
    __syncthreads();

    // Phase 4: write PURE parent (1 px-quad per thread); roots also zero cnt
    //          + append (groot,size-1) to list
    int* P = parent + (size_t)b * HW;
    {
        int i = t;                                // TN/4 == 1024 == blockDim
        int r = i >> 4, c4 = (i & 15) * 4;
        unsigned long long m = msk[r];
        int w[4];
#pragma unroll
        for (int j = 0; j < 4; ++j) {
            int c = c4 + j, l = r * TW + c;
            if (!((m >> c) & 1ull)) { w[j] = SENT_P; continue; }
            int node = r * TW + runstart64(m, c);
            int root = lfindm(lp, node);
            int groot = (tr0 + (root >> 6)) * WW + tc0 + (root & (TW - 1));
            w[j] = groot;                              // PURE (root -> self)
            if (l == root) {
                int size = lp[root] >> 16;             // 1..4096
                cnt[(size_t)b * HW + groot] = 0;       // zero-init (plain)
                int idx = atomicAdd(&rootcnt[b], 1);
                list[b * LIST_STRIDE + idx] = groot | ((size - 1) << 16);
            }
        }
        *(int4*)(P + (tr0 + r) * WW + tc0 + c4) = make_int4(w[0], w[1], w[2], w[3]);
    }
}

// ---- K3: boundary merge — PURE atomicMin linking (R14-proven) ----
__device__ __forceinline__ int findroot_h(int* P, int x) {
    int p = aload(P + x);
    while (p != x) {
        int gp = aload(P + p);
        astore(P + x, gp);
        x = gp; p = aload(P + x);
    }
    return x;
}
__device__ __forceinline__ void unite(int* P, int a, int b) {
    int ra = findroot_h(P, a);
    int rb = findroot_h(P, b);
    while (ra != rb) {
        int lo = min(ra, rb), hi = max(ra, rb);
        int old = atomicMin(&P[hi], lo);
        if (old == hi) return;
        ra = findroot_h(P, lo);
        rb = findroot_h(P, old);
    }
}
__global__ void k_bmerge(int* parent) {
    int g = blockIdx.x * blockDim.x + threadIdx.x;
    if (g >= BATCH * 1536) return;
    int b = g / 1536, e = g % 1536;
    int* P = parent + (size_t)b * HW;
    int l, m;
    if (e < 768) {          // vertical edges: cols {63,127,191}
        int k = e / 256, row = e & 255;
        l = row * WW + (TW - 1 + TW * k); m = l + 1;
    } else {                // horizontal edges: rows {63,127,191}
        int e2 = e - 768;
        int k = e2 / 256, col = e2 & 255;
        l = (TH - 1 + TH * k) * WW + col; m = l + WW;
    }
    if (aload(P + l) != SENT_P && aload(P + m) != SENT_P) unite(P, l, m);
}

// ---- K4: accumulate — one thread per tile root: walk frozen parent, one add ----
__global__ void k_acc(const int* __restrict__ parent, int* __restrict__ cnt,
                      const int* __restrict__ list, const int* __restrict__ rootcnt) {
    int g = blockIdx.x * blockDim.x + threadIdx.x;
    int b = g / LIST_STRIDE, i = g - b * LIST_STRIDE;
    if (b >= BATCH || i >= rootcnt[b]) return;
    int e = list[b * LIST_STRIDE + i];
    int x = e & 0xFFFF;
    int size = (e >> 16) + 1;
    const int* P = parent + (size_t)b * HW;
    int p = P[x];                              // plain loads: topology frozen
    while (p != x) { x = p; p = P[x]; }
    atomicAdd(&cnt[(size_t)b * HW + x], size); // fire-and-forget, memory-side
}

// ---- K5: finalize — plain L1-hot walk + cnt lookup; hw exp2/log2 pow ----
__global__ void k_final(const float* __restrict__ att, const int* __restrict__ parent,
                        const int* __restrict__ cnt, float* __restrict__ out) {
    int g = blockIdx.x * blockDim.x + threadIdx.x;
    int base = g * 4;
    if (base >= NPIX) return;
    const int* P = parent + (base & ~(HW - 1));
    const int* C = cnt + (base & ~(HW - 1));
    float4 v = ((const float4*)att)[g];
    int4 pv = ((const int4*)parent)[g];
    int vv[4] = {pv.x, pv.y, pv.z, pv.w};
    float xs[4] = {v.x, v.y, v.z, v.w};
    float ys[4];
#pragma unroll
    for (int j = 0; j < 4; ++j) {
        float x = xs[j];
        int w = vv[j];
        if (w == SENT_P) { ys[j] = x; continue; }
        int xi = w, p = P[xi];
        while (p != xi) { xi = p; p = P[xi]; }     // depth ~1-2 post-halving
        int a = C[xi];
        if (a <= 1) { ys[j] = x; continue; }       // x^1 == x
        float e = 1.0f / sqrtf((float)a);
        // x > thr >= 0 here; v_log_f32/v_exp_f32: |err| ~ |log2 x|*ulp << 2e-2
        ys[j] = __builtin_amdgcn_exp2f(e * __builtin_amdgcn_logf(x));
    }
    ((float4*)out)[g] = make_float4(ys[0], ys[1], ys[2], ys[3]);
}

// ================= fallback (tiny ws): R11-proven monolith =================
__global__ __launch_bounds__(1024)
void k_all(const float* __restrict__ att, float* out) {
    const int b = blockIdx.x;
    const int t = threadIdx.x;
    const float* A = att + (size_t)b * HW;
    int* L = (int*)out + (size_t)b * HW;
    __shared__ int hist[NBINS];
    __shared__ double s_thr;
    __shared__ int s_changed;
    for (int i = t; i < NBINS; i += 1024) hist[i] = 0;
    if (t == 0) s_changed = 0;
    __syncthreads();
    const float4* src4 = (const float4*)A;
    for (int i = t; i < HW / 4; i += 1024) {
        float4 v = src4[i];
        atomicAdd(&hist[min((int)(v.x * 50.0f), 49)], 1);
        atomicAdd(&hist[min((int)(v.y * 50.0f), 49)], 1);
        atomicAdd(&hist[min((int)(v.z * 50.0f), 49)], 1);
        atomicAdd(&hist[min((int)(v.w * 50.0f), 49)], 1);
    }
    __syncthreads();
    if (t == 0) {
        int ind_max = 0, bv = hist[0];
        for (int j = 1; j < NBINS; ++j)
            if (hist[j] > bv) { bv = hist[j]; ind_max = j; }
        int ind_sec = 0, bv2 = -1;
        for (int j = 1; j < NBINS; ++j) {
            int v = (j > ind_max) ? hist[j] : -1;
            if (v > bv2) { bv2 = v; ind_sec = j; }
        }
        s_thr = (double)ind_sec / 50.0;
    }
    __syncthreads();
    const double tv = s_thr;
    for (int i = t; i < HW / 4; i += 1024) {
        float4 v = src4[i];
        int l = i * 4;
        astore(L + l + 0, ((double)v.x > tv) ? (l + 0) : SENT_P);
        astore(L + l + 1, ((double)v.y > tv) ? (l + 1) : SENT_P);
        astore(L + l + 2, ((double)v.z > tv) ? (l + 2) : SENT_P);
        astore(L + l + 3, ((double)v.w > tv) ? (l + 3) : SENT_P);
    }
    __syncthreads();
    for (;;) {
        int changed = 0;
        for (int p = t; p < HW; p += 1024) {
            int v = aload(L + p);
            if (v == SENT_P) continue;
            int m = v;
            int col = p & (WW - 1), row = p >> 8;
            if (col > 0)      m = min(m, aload(L + p - 1));
            if (col < WW - 1) m = min(m, aload(L + p + 1));
            if (row > 0)      m = min(m, aload(L + p - WW));
            if (row < HH - 1) m = min(m, aload(L + p + WW));
            m = min(m, aload(L + m));
            if (m < v) { astore(L + p, m); changed = 1; }
        }
        if (changed) s_changed = 1;
        __syncthreads();
        int ch = s_changed;
        __syncthreads();
        if (!ch) break;
        if (t == 0) s_changed = 0;
        __syncthreads();
    }
    for (int p = t; p < HW; p += 1024) {
        int v = aload(L + p);
        if (v == SENT_P) continue;
        int lo = v & 0xFFFF;
        if (lo != p) atomicAdd((unsigned int*)(L + lo), 0x10000u);
    }
    __syncthreads();
    for (int p = t; p < HW; p += 1024) {
        int v = aload(L + p);
        if (v == SENT_P) continue;
        int lo = v & 0xFFFF;
        if (lo != p) astore(L + p, aload(L + lo));
    }
    __syncthreads();
    for (int p = t; p < HW; p += 1024) {
        float x = A[p];
        unsigned v = (unsigned)aload(L + p);
        float y = x;
        if (v != (unsigned)SENT_P) {
            float a = (float)((v >> 16) + 1u);
            y = powf(x, 1.0f / sqrtf(a));
        }
        out[(size_t)b * HW + p] = y;
    }
}

extern "C" void kernel_launch(void* const* d_in, const int* in_sizes, int n_in,
                              void* d_out, int out_size, void* d_ws, size_t ws_size,
                              hipStream_t stream) {
    const float* att = (const float*)d_in[0];
    float* out = (float*)d_out;
    (void)in_sizes; (void)n_in; (void)out_size;

    const size_t PAR_B  = (size_t)NPIX * 4;                 // 16 MB
    const size_t CNT_B  = (size_t)NPIX * 4;                 // 16 MB
    const size_t LIST_B = (size_t)BATCH * LIST_STRIDE * 4;  // 8 MB
    const size_t HIST_B = (size_t)BATCH * 8 * 64 * 4;       // 128 KB
    if (ws_size < PAR_B + CNT_B + LIST_B + HIST_B + 1024) {
        k_all<<<BATCH, 1024, 0, stream>>>(att, out);        // proven fallback
        return;
    }
    int* parent  = (int*)d_ws;
    int* cnt     = (int*)((char*)d_ws + PAR_B);
    int* list    = (int*)((char*)d_ws + PAR_B + CNT_B);
    int* histp   = (int*)((char*)d_ws + PAR_B + CNT_B + LIST_B);
    int* rootcnt = (int*)((char*)d_ws + PAR_B + CNT_B + LIST_B + HIST_B);

    k_hist<<<dim3(8, BATCH), 256, 0, stream>>>(att, histp, rootcnt);
    k_init_cc<<<dim3(TILES_PER_IMG, BATCH), 1024, 0, stream>>>(att, histp, parent,
                                                               cnt, list, rootcnt);
    k_bmerge<<<(BATCH * 1536 + 255) / 256, 256, 0, stream>>>(parent);
    k_acc<<<(BATCH * LIST_STRIDE) / 256, 256, 0, stream>>>(parent, cnt, list, rootcnt);
    k_final<<<NPIX / (256 * 4), 256, 0, stream>>>(att, parent, cnt, out);
}

// Round 29
// 81.320 us; speedup vs baseline: 8.2281x; 1.0294x over previous
//
#include <hip/hip_runtime.h>
#include <math.h>

#define BATCH 64
#define HH 256
#define WW 256
#define HW 65536            // 256*256 pixels per image
#define NPIX (BATCH * HW)   // 4194304
#define NBINS 50
#define SENT_P 0x7FFFFFFF   // background marker

#define TW 64
#define TH 64
#define TN (TW * TH)
#define TILES_X (WW / TW)   // 4
#define TILES_PER_IMG 16
#define LIST_STRIDE 32768   // max tile-roots per image

__device__ __forceinline__ int aload(const int* p) {
    return __hip_atomic_load(p, __ATOMIC_RELAXED, __HIP_MEMORY_SCOPE_AGENT);
}
__device__ __forceinline__ void astore(int* p, int v) {
    __hip_atomic_store(p, v, __ATOMIC_RELAXED, __HIP_MEMORY_SCOPE_AGENT);
}

__device__ __forceinline__ int runstart64(unsigned long long m, int c) {
    unsigned long long sh = (~m) << (63 - c);
    return sh ? (c - __clzll(sh) + 1) : 0;
}
__device__ __forceinline__ int runlen64(unsigned long long m, int c) {
    unsigned long long sh = ~(m >> c);
    return sh ? (__ffsll(sh) - 1) : 64;
}
// wave argmax: max val, tie -> min idx (== np first-occurrence)
__device__ __forceinline__ void wave_argmax(int& bv, int& bi) {
#pragma unroll
    for (int off = 32; off > 0; off >>= 1) {
        int ov = __shfl_xor(bv, off);
        int oi = __shfl_xor(bi, off);
        if (ov > bv || (ov == bv && oi < bi)) { bv = ov; bi = oi; }
    }
}

// ---- K1: histogram partials (8 blocks/image) + zero per-image root counter ----
__global__ void k_hist(const float* __restrict__ att, int* __restrict__ histp,
                       int* __restrict__ rootcnt) {
    __shared__ int h[NBINS];
    const int b = blockIdx.y, c = blockIdx.x, t = threadIdx.x;
    if (c == 0 && t == 0) rootcnt[b] = 0;       // published at kernel boundary
    if (t < NBINS) h[t] = 0;
    __syncthreads();
    const float4* src = (const float4*)(att + (size_t)b * HW) + c * 2048;
    for (int i = t; i < 2048; i += 256) {
        float4 v = src[i];
        atomicAdd(&h[min((int)(v.x * 50.0f), 49)], 1);
        atomicAdd(&h[min((int)(v.y * 50.0f), 49)], 1);
        atomicAdd(&h[min((int)(v.z * 50.0f), 49)], 1);
        atomicAdd(&h[min((int)(v.w * 50.0f), 49)], 1);
    }
    __syncthreads();
    if (t < NBINS) histp[(b * 8 + c) * 64 + t] = h[t];
}

// ---- LDS union-find over run-start nodes ----
__device__ __forceinline__ void lunite(int* lp, int a, int b) {
    int x = a, p = lp[x];
    while (p != x) { int gp = lp[p]; if (gp != p) lp[x] = gp; x = gp; p = lp[x]; }
    int ra = x;
    x = b; p = lp[x];
    while (p != x) { int gp = lp[p]; if (gp != p) lp[x] = gp; x = gp; p = lp[x]; }
    int rb = x;
    while (ra != rb) {
        int lo = min(ra, rb), hi = max(ra, rb);
        int old = atomicMin(&lp[hi], lo);
        if (old == hi) return;
        x = lo; p = lp[x];
        while (p != x) { int gp = lp[p]; if (gp != p) lp[x] = gp; x = gp; p = lp[x]; }
        ra = x;
        x = old; p = lp[x];
        while (p != x) { int gp = lp[p]; if (gp != p) lp[x] = gp; x = gp; p = lp[x]; }
        rb = x;
    }
}
// masked find (after length deposits: root slots carry size in high bits)
__device__ __forceinline__ int lfindm(int* lp, int x) {
    while (true) {
        int p = lp[x] & 0xFFFF;
        if (p == x) return x;
        int gp = lp[p] & 0xFFFF;
        if (gp != p) lp[x] = gp;
        x = gp;
    }
}

// ---- K2: fused threshold + run-based tile CC (1024 threads) ----
// R29 change: the per-root list-append no longer does a RETURNING global
// atomicAdd per root (~2000 same-address RMWs/image serialized at the L2 RMW
// unit — the layout-invariant 41 µs). Roots take a block-local rank via LDS
// atomic; ONE global atomicAdd per block (16/image) claims the list range.
__global__ __launch_bounds__(1024)
void k_init_cc(const float* __restrict__ att, const int* __restrict__ histp,
               int* parent, int* __restrict__ cnt, int* __restrict__ list,
               int* __restrict__ rootcnt) {
    __shared__ int lp[TN];
    __shared__ unsigned long long msk[TH];
    __shared__ int s_nroots, s_base;
    const int tile = blockIdx.x;
    const int b = blockIdx.y;
    const int t = threadIdx.x;
    const int wv = t >> 6, ln = t & 63;          // 16 waves
    const int tr0 = (tile / TILES_X) * TH;
    const int tc0 = (tile % TILES_X) * TW;
    const float* A = att + (size_t)b * HW;

    // Phase 0: per-wave inline threshold (R11-proven f64 semantics)
    int h_ln = 0;
    if (ln < NBINS)
        for (int c = 0; c < 8; ++c) h_ln += histp[(b * 8 + c) * 64 + ln];
    int bv = (ln < NBINS) ? h_ln : -1, bi = ln;
    wave_argmax(bv, bi);
    const int ind_max = bi;
    int bv2 = (ln < NBINS && ln > ind_max) ? h_ln : -1, bi2 = ln;
    wave_argmax(bv2, bi2);
    const double tv = (double)bi2 / 50.0;

    // Phase 1: row masks + lp init at run starts (4 rows per wave)
#pragma unroll
    for (int k = 0; k < 4; ++k) {
        int r = wv + 16 * k;
        float x = A[(tr0 + r) * WW + tc0 + ln];
        bool fg = (double)x > tv;
        unsigned long long m = __ballot(fg);
        if (ln == 0) msk[r] = m;
        if (fg && (ln == 0 || !((m >> (ln - 1)) & 1ull)))
            lp[r * TW + ln] = r * TW + ln;
    }
    __syncthreads();

    // Phase 2: vertical unions, one per overlap segment
#pragma unroll
    for (int k = 0; k < 4; ++k) {
        int r = wv + 16 * k;
        if (r >= TH - 1) continue;
        unsigned long long m0 = msk[r], m1 = msk[r + 1];
        unsigned long long ov = m0 & m1;
        if (((ov >> ln) & 1ull) && (ln == 0 || !((ov >> (ln - 1)) & 1ull)))
            lunite(lp, r * TW + runstart64(m0, ln),
                       (r + 1) * TW + runstart64(m1, ln));
    }
    if (t == 0) s_nroots = 0;        // nobody reads until after Phase-3 barrier
    __syncthreads();

    // Phase 3: deposit run lengths at local roots
#pragma unroll
    for (int k = 0; k < 4; ++k) {
        int r = wv + 16 * k;
        unsigned long long m = msk[r];
        if (((m >> ln) & 1ull) && (ln == 0 || !((m >> (ln - 1)) & 1ull))) {
            int L = runlen64(m, ln);
            int root = lfindm(lp, r * TW + ln);
            atomicAdd(&lp[root], L << 16);
        }
    }
    __syncthreads();

    // Phase 4a: write PURE parent (1 px-quad/thread); roots take LDS ranks,
    //           cache (groot,size) in two scalar slots (no dynamic indexing)
    int* P = parent + (size_t)b * HW;
    int g0 = -1, z0 = 0, k0 = 0;
    int g1 = -1, z1 = 0, k1 = 0;
    {
        int i = t;                                // TN/4 == 1024 == blockDim
        int r = i >> 4, c4 = (i & 15) * 4;
        unsigned long long m = msk[r];
        int w[4];
#pragma unroll
        for (int j = 0; j < 4; ++j) {
            int c = c4 + j, l = r * TW + c;
            if (!((m >> c) & 1ull)) { w[j] = SENT_P; continue; }
            int node = r * TW + runstart64(m, c);
            int root = lfindm(lp, node);
            int groot = (tr0 + (root >> 6)) * WW + tc0 + (root & (TW - 1));
            w[j] = groot;                              // PURE (root -> self)
            if (l == root) {                           // <= 2 roots per thread
                int size = lp[root] >> 16;             // 1..4096
                cnt[(size_t)b * HW + groot] = 0;       // zero-init (plain)
                int rank = atomicAdd(&s_nroots, 1);    // LDS atomic (block-local)
                if (g0 < 0) { g0 = groot; z0 = size; k0 = rank; }
                else        { g1 = groot; z1 = size; k1 = rank; }
            }
        }
        *(int4*)(P + (tr0 + r) * WW + tc0 + c4) = make_int4(w[0], w[1], w[2], w[3]);
    }
    __syncthreads();
    if (t == 0) s_base = atomicAdd(&rootcnt[b], s_nroots);   // 16 RMWs/image total
    __syncthreads();

    // Phase 4b: write cached roots into claimed list range
    {
        int base = b * LIST_STRIDE + s_base;
        if (g0 >= 0) list[base + k0] = g0 | ((z0 - 1) << 16);
        if (g1 >= 0) list[base + k1] = g1 | ((z1 - 1) << 16);
    }
}

// ---- K3: boundary merge — PURE atomicMin linking (R14-proven) ----
__device__ __forceinline__ int findroot_h(int* P, int x) {
    int p = aload(P + x);
    while (p != x) {
        int gp = aload(P + p);
        astore(P + x, gp);
        x = gp; p = aload(P + x);
    }
    return x;
}
__device__ __forceinline__ void unite(int* P, int a, int b) {
    int ra = findroot_h(P, a);
    int rb = findroot_h(P, b);
    while (ra != rb) {
        int lo = min(ra, rb), hi = max(ra, rb);
        int old = atomicMin(&P[hi], lo);
        if (old == hi) return;
        ra = findroot_h(P, lo);
        rb = findroot_h(P, old);
    }
}
__global__ void k_bmerge(int* parent) {
    int g = blockIdx.x * blockDim.x + threadIdx.x;
    if (g >= BATCH * 1536) return;
    int b = g / 1536, e = g % 1536;
    int* P = parent + (size_t)b * HW;
    int l, m;
    if (e < 768) {          // vertical edges: cols {63,127,191}
        int k = e / 256, row = e & 255;
        l = row * WW + (TW - 1 + TW * k); m = l + 1;
    } else {                // horizontal edges: rows {63,127,191}
        int e2 = e - 768;
        int k = e2 / 256, col = e2 & 255;
        l = (TH - 1 + TH * k) * WW + col; m = l + WW;
    }
    if (aload(P + l) != SENT_P && aload(P + m) != SENT_P) unite(P, l, m);
}

// ---- K4: accumulate — one thread per tile root: walk frozen parent, one add ----
__global__ void k_acc(const int* __restrict__ parent, int* __restrict__ cnt,
                      const int* __restrict__ list, const int* __restrict__ rootcnt) {
    int g = blockIdx.x * blockDim.x + threadIdx.x;
    int b = g / LIST_STRIDE, i = g - b * LIST_STRIDE;
    if (b >= BATCH || i >= rootcnt[b]) return;
    int e = list[b * LIST_STRIDE + i];
    int x = e & 0xFFFF;
    int size = (e >> 16) + 1;
    const int* P = parent + (size_t)b * HW;
    int p = P[x];                              // plain loads: topology frozen
    while (p != x) { x = p; p = P[x]; }
    atomicAdd(&cnt[(size_t)b * HW + x], size); // fire-and-forget, memory-side
}

// ---- K5: finalize — plain L1-hot walk + cnt lookup; hw exp2/log2 pow ----
__global__ void k_final(const float* __restrict__ att, const int* __restrict__ parent,
                        const int* __restrict__ cnt, float* __restrict__ out) {
    int g = blockIdx.x * blockDim.x + threadIdx.x;
    int base = g * 4;
    if (base >= NPIX) return;
    const int* P = parent + (base & ~(HW - 1));
    const int* C = cnt + (base & ~(HW - 1));
    float4 v = ((const float4*)att)[g];
    int4 pv = ((const int4*)parent)[g];
    int vv[4] = {pv.x, pv.y, pv.z, pv.w};
    float xs[4] = {v.x, v.y, v.z, v.w};
    float ys[4];
#pragma unroll
    for (int j = 0; j < 4; ++j) {
        float x = xs[j];
        int w = vv[j];
        if (w == SENT_P) { ys[j] = x; continue; }
        int xi = w, p = P[xi];
        while (p != xi) { xi = p; p = P[xi]; }     // depth ~1-2 post-halving
        int a = C[xi];
        if (a <= 1) { ys[j] = x; continue; }       // x^1 == x
        float e = 1.0f / sqrtf((float)a);
        // x > thr >= 0 here; v_log_f32/v_exp_f32: |err| ~ |log2 x|*ulp << 2e-2
        ys[j] = __builtin_amdgcn_exp2f(e * __builtin_amdgcn_logf(x));
    }
    ((float4*)out)[g] = make_float4(ys[0], ys[1], ys[2], ys[3]);
}

// ================= fallback (tiny ws): R11-proven monolith =================
__global__ __launch_bounds__(1024)
void k_all(const float* __restrict__ att, float* out) {
    const int b = blockIdx.x;
    const int t = threadIdx.x;
    const float* A = att + (size_t)b * HW;
    int* L = (int*)out + (size_t)b * HW;
    __shared__ int hist[NBINS];
    __shared__ double s_thr;
    __shared__ int s_changed;
    for (int i = t; i < NBINS; i += 1024) hist[i] = 0;
    if (t == 0) s_changed = 0;
    __syncthreads();
    const float4* src4 = (const float4*)A;
    for (int i = t; i < HW / 4; i += 1024) {
        float4 v = src4[i];
        atomicAdd(&hist[min((int)(v.x * 50.0f), 49)], 1);
        atomicAdd(&hist[min((int)(v.y * 50.0f), 49)], 1);
        atomicAdd(&hist[min((int)(v.z * 50.0f), 49)], 1);
        atomicAdd(&hist[min((int)(v.w * 50.0f), 49)], 1);
    }
    __syncthreads();
    if (t == 0) {
        int ind_max = 0, bv = hist[0];
        for (int j = 1; j < NBINS; ++j)
            if (hist[j] > bv) { bv = hist[j]; ind_max = j; }
        int ind_sec = 0, bv2 = -1;
        for (int j = 1; j < NBINS; ++j) {
            int v = (j > ind_max) ? hist[j] : -1;
            if (v > bv2) { bv2 = v; ind_sec = j; }
        }
        s_thr = (double)ind_sec / 50.0;
    }
    __syncthreads();
    const double tv = s_thr;
    for (int i = t; i < HW / 4; i += 1024) {
        float4 v = src4[i];
        int l = i * 4;
        astore(L + l + 0, ((double)v.x > tv) ? (l + 0) : SENT_P);
        astore(L + l + 1, ((double)v.y > tv) ? (l + 1) : SENT_P);
        astore(L + l + 2, ((double)v.z > tv) ? (l + 2) : SENT_P);
        astore(L + l + 3, ((double)v.w > tv) ? (l + 3) : SENT_P);
    }
    __syncthreads();
    for (;;) {
        int changed = 0;
        for (int p = t; p < HW; p += 1024) {
            int v = aload(L + p);
            if (v == SENT_P) continue;
            int m = v;
            int col = p & (WW - 1), row = p >> 8;
            if (col > 0)      m = min(m, aload(L + p - 1));
            if (col < WW - 1) m = min(m, aload(L + p + 1));
            if (row > 0)      m = min(m, aload(L + p - WW));
            if (row < HH - 1) m = min(m, aload(L + p + WW));
            m = min(m, aload(L + m));
            if (m < v) { astore(L + p, m); changed = 1; }
        }
        if (changed) s_changed = 1;
        __syncthreads();
        int ch = s_changed;
        __syncthreads();
        if (!ch) break;
        if (t == 0) s_changed = 0;
        __syncthreads();
    }
    for (int p = t; p < HW; p += 1024) {
        int v = aload(L + p);
        if (v == SENT_P) continue;
        int lo = v & 0xFFFF;
        if (lo != p) atomicAdd((unsigned int*)(L + lo), 0x10000u);
    }
    __syncthreads();
    for (int p = t; p < HW; p += 1024) {
        int v = aload(L + p);
        if (v == SENT_P) continue;
        int lo = v & 0xFFFF;
        if (lo != p) astore(L + p, aload(L + lo));
    }
    __syncthreads();
    for (int p = t; p < HW; p += 1024) {
        float x = A[p];
        unsigned v = (unsigned)aload(L + p);
        float y = x;
        if (v != (unsigned)SENT_P) {
            float a = (float)((v >> 16) + 1u);
            y = powf(x, 1.0f / sqrtf(a));
        }
        out[(size_t)b * HW + p] = y;
    }
}

extern "C" void kernel_launch(void* const* d_in, const int* in_sizes, int n_in,
                              void* d_out, int out_size, void* d_ws, size_t ws_size,
                              hipStream_t stream) {
    const float* att = (const float*)d_in[0];
    float* out = (float*)d_out;
    (void)in_sizes; (void)n_in; (void)out_size;

    const size_t PAR_B  = (size_t)NPIX * 4;                 // 16 MB
    const size_t CNT_B  = (size_t)NPIX * 4;                 // 16 MB
    const size_t LIST_B = (size_t)BATCH * LIST_STRIDE * 4;  // 8 MB
    const size_t HIST_B = (size_t)BATCH * 8 * 64 * 4;       // 128 KB
    if (ws_size < PAR_B + CNT_B + LIST_B + HIST_B + 1024) {
        k_all<<<BATCH, 1024, 0, stream>>>(att, out);        // proven fallback
        return;
    }
    int* parent  = (int*)d_ws;
    int* cnt     = (int*)((char*)d_ws + PAR_B);
    int* list    = (int*)((char*)d_ws + PAR_B + CNT_B);
    int* histp   = (int*)((char*)d_ws + PAR_B + CNT_B + LIST_B);
    int* rootcnt = (int*)((char*)d_ws + PAR_B + CNT_B + LIST_B + HIST_B);

    k_hist<<<dim3(8, BATCH), 256, 0, stream>>>(att, histp, rootcnt);
    k_init_cc<<<dim3(TILES_PER_IMG, BATCH), 1024, 0, stream>>>(att, histp, parent,
                                                               cnt, list, rootcnt);
    k_bmerge<<<(BATCH * 1536 + 255) / 256, 256, 0, stream>>>(parent);
    k_acc<<<(BATCH * LIST_STRIDE) / 256, 256, 0, stream>>>(parent, cnt, list, rootcnt);
    k_final<<<NPIX / (256 * 4), 256, 0, stream>>>(att, parent, cnt, out);
}